// Round 7
// baseline (485.814 us; speedup 1.0000x reference)
//
#include <hip/hip_runtime.h>
#include <hip/hip_bf16.h>
#include <math.h>

#define NN 50000
#define NE 800000

__device__ __forceinline__ float lrelu(float x) { return x > 0.f ? x : 0.2f * x; }

// ---------------- fused dual GEMM: Xl = A@Wl + bl, Xr = A@Wr + br ----------
// Block tile 64 rows x 256 cols, 256 threads, micro-tile 4x16 (cols q*64+tx*4).
// Ws staging uses flat index j*256+tid so consecutive lanes write consecutive
// float4s (old layout had all 64 lanes in one 4-bank group: ~16-way conflict).
__global__ __launch_bounds__(256) void gemm_fused(
    const float* __restrict__ A, const float* __restrict__ Wl,
    const float* __restrict__ bl, const float* __restrict__ Wr,
    const float* __restrict__ br, float* __restrict__ Xl,
    float* __restrict__ Xr, int n) {
  __shared__ float As[64][36];
  __shared__ float Ws[32][256];
  const int tid = threadIdx.x;
  const int tx = tid & 15;
  const int ty = tid >> 4;
  const int r0 = blockIdx.x * 64;

  float acc[4][16];
#pragma unroll
  for (int j = 0; j < 4; j++)
#pragma unroll
    for (int q = 0; q < 16; q++) acc[j][q] = 0.f;

  for (int kt = 0; kt < 4; ++kt) {
    // stage A tile (64 x 32)
    {
      int row = tid >> 2;
      int kq = (tid & 3) * 8;
      int gr = r0 + row;
      float4 a0, a1;
      if (gr < n) {
        a0 = *(const float4*)&A[gr * 128 + kt * 32 + kq];
        a1 = *(const float4*)&A[gr * 128 + kt * 32 + kq + 4];
      } else {
        a0 = make_float4(0.f, 0.f, 0.f, 0.f);
        a1 = a0;
      }
      *(float4*)&As[row][kq] = a0;
      *(float4*)&As[row][kq + 4] = a1;
    }
    // stage W tile (32 x 256): 2048 float4s, lane-consecutive -> conflict-free
#pragma unroll
    for (int j = 0; j < 8; j++) {
      int f = j * 256 + tid;     // float4 index
      int kr = f >> 6;           // row 0..31
      int c = (f & 63) * 4;      // col 0..252
      int gk = kt * 32 + kr;
      const float* Wsrc = (c < 128) ? &Wl[gk * 128 + c] : &Wr[gk * 128 + (c - 128)];
      *(float4*)&Ws[kr][c] = *(const float4*)Wsrc;
    }
    __syncthreads();

#pragma unroll 8
    for (int k = 0; k < 32; k++) {
      float a0 = As[ty * 4 + 0][k];
      float a1 = As[ty * 4 + 1][k];
      float a2 = As[ty * 4 + 2][k];
      float a3 = As[ty * 4 + 3][k];
#pragma unroll
      for (int q = 0; q < 4; q++) {
        float4 w = *(const float4*)&Ws[k][q * 64 + tx * 4];
        acc[0][4 * q + 0] += a0 * w.x; acc[0][4 * q + 1] += a0 * w.y;
        acc[0][4 * q + 2] += a0 * w.z; acc[0][4 * q + 3] += a0 * w.w;
        acc[1][4 * q + 0] += a1 * w.x; acc[1][4 * q + 1] += a1 * w.y;
        acc[1][4 * q + 2] += a1 * w.z; acc[1][4 * q + 3] += a1 * w.w;
        acc[2][4 * q + 0] += a2 * w.x; acc[2][4 * q + 1] += a2 * w.y;
        acc[2][4 * q + 2] += a2 * w.z; acc[2][4 * q + 3] += a2 * w.w;
        acc[3][4 * q + 0] += a3 * w.x; acc[3][4 * q + 1] += a3 * w.y;
        acc[3][4 * q + 2] += a3 * w.z; acc[3][4 * q + 3] += a3 * w.w;
      }
    }
    __syncthreads();
  }

#pragma unroll
  for (int j = 0; j < 4; j++) {
    int gr = r0 + ty * 4 + j;
    if (gr >= n) continue;
#pragma unroll
    for (int q = 0; q < 4; q++) {
      int c = q * 64 + tx * 4;
      float4 v;
      if (c < 128) {
        v.x = acc[j][4 * q + 0] + bl[c + 0];
        v.y = acc[j][4 * q + 1] + bl[c + 1];
        v.z = acc[j][4 * q + 2] + bl[c + 2];
        v.w = acc[j][4 * q + 3] + bl[c + 3];
        *(float4*)&Xl[gr * 128 + c] = v;
      } else {
        int cc = c - 128;
        v.x = acc[j][4 * q + 0] + br[cc + 0];
        v.y = acc[j][4 * q + 1] + br[cc + 1];
        v.z = acc[j][4 * q + 2] + br[cc + 2];
        v.w = acc[j][4 * q + 3] + br[cc + 3];
        *(float4*)&Xr[gr * 128 + cc] = v;
      }
    }
  }
}

// ---------------- CSR build ----------------
__global__ void zero_i32(int* p, int n) {
  int i = blockIdx.x * 256 + threadIdx.x;
  if (i < n) p[i] = 0;
}

__global__ void hist_kernel(const int* __restrict__ dst, int* __restrict__ deg) {
  int e = blockIdx.x * 256 + threadIdx.x;
  if (e < NE) atomicAdd(&deg[dst[e]], 1);
}

__global__ __launch_bounds__(256) void scan_a(const int* __restrict__ in,
                                              int* __restrict__ excl,
                                              int* __restrict__ bsum, int n) {
  int i = blockIdx.x * 256 + threadIdx.x;
  int v = (i < n) ? in[i] : 0;
  int lane = threadIdx.x & 63, wid = threadIdx.x >> 6;
  int incl = v;
#pragma unroll
  for (int off = 1; off < 64; off <<= 1) {
    int u = __shfl_up(incl, off);
    if (lane >= off) incl += u;
  }
  __shared__ int wsum[4];
  if (lane == 63) wsum[wid] = incl;
  __syncthreads();
  int wo = 0;
  for (int w = 0; w < wid; w++) wo += wsum[w];
  if (i < n) excl[i] = wo + incl - v;
  if (threadIdx.x == 255 && bsum) bsum[blockIdx.x] = wo + incl;
}

__global__ void scan_c(int* __restrict__ rowptr, const int* __restrict__ boff,
                       int* __restrict__ cursor, int n) {
  int i = blockIdx.x * 256 + threadIdx.x;
  if (i < n) {
    int v = rowptr[i] + boff[i >> 8];
    rowptr[i] = v;
    cursor[i] = v;
  } else if (i == n) {
    rowptr[n] = NE;
  }
}

__global__ void scatter_kernel(const int* __restrict__ src, const int* __restrict__ dst,
                               int* __restrict__ cursor, int* __restrict__ ssort) {
  int e = blockIdx.x * 256 + threadIdx.x;
  if (e >= NE) return;
  int p = atomicAdd(&cursor[dst[e]], 1);
  ssort[p] = src[e];
}

// ------- fused: logits + segment-softmax + aggregate + bias + ELU ---------
__global__ __launch_bounds__(256) void gat_aggregate_fused(
    const float* __restrict__ Xl, const float* __restrict__ Xr,
    const float* __restrict__ att, const int* __restrict__ ssort,
    const int* __restrict__ rowptr, const float* __restrict__ bias,
    float* __restrict__ out) {
  int slot = threadIdx.x >> 5;
  int l = threadIdx.x & 31;
  int n = blockIdx.x * 8 + slot;
  if (n >= NN) return;
  int s0 = rowptr[n], s1 = rowptr[n + 1];
  float4 xr = *(const float4*)&Xr[n * 128 + l * 4];
  float4 at = *(const float4*)&att[l * 4];

  float den0 = 0.f, den1 = 0.f;
  float4 A0 = make_float4(0.f, 0.f, 0.f, 0.f);
  float4 A1 = make_float4(0.f, 0.f, 0.f, 0.f);

  int i = s0;
  for (; i + 4 <= s1; i += 4) {
    int sa = ssort[i], sb = ssort[i + 1], sc = ssort[i + 2], sd = ssort[i + 3];
    float4 xa = *(const float4*)&Xl[sa * 128 + l * 4];
    float4 xb = *(const float4*)&Xl[sb * 128 + l * 4];
    float4 xc = *(const float4*)&Xl[sc * 128 + l * 4];
    float4 xd = *(const float4*)&Xl[sd * 128 + l * 4];
    float pa = at.x * lrelu(xa.x + xr.x) + at.y * lrelu(xa.y + xr.y) +
               at.z * lrelu(xa.z + xr.z) + at.w * lrelu(xa.w + xr.w);
    float pb = at.x * lrelu(xb.x + xr.x) + at.y * lrelu(xb.y + xr.y) +
               at.z * lrelu(xb.z + xr.z) + at.w * lrelu(xb.w + xr.w);
    float pc = at.x * lrelu(xc.x + xr.x) + at.y * lrelu(xc.y + xr.y) +
               at.z * lrelu(xc.z + xr.z) + at.w * lrelu(xc.w + xr.w);
    float pd = at.x * lrelu(xd.x + xr.x) + at.y * lrelu(xd.y + xr.y) +
               at.z * lrelu(xd.z + xr.z) + at.w * lrelu(xd.w + xr.w);
#pragma unroll
    for (int off = 1; off <= 4; off <<= 1) {
      pa += __shfl_xor(pa, off);
      pb += __shfl_xor(pb, off);
      pc += __shfl_xor(pc, off);
      pd += __shfl_xor(pd, off);
    }
    float wa = __expf(fminf(pa, 30.f));
    float wb = __expf(fminf(pb, 30.f));
    float wc = __expf(fminf(pc, 30.f));
    float wd = __expf(fminf(pd, 30.f));
    den0 += wa + wc;
    den1 += wb + wd;
    A0.x += wa * xa.x + wc * xc.x;  A1.x += wb * xb.x + wd * xd.x;
    A0.y += wa * xa.y + wc * xc.y;  A1.y += wb * xb.y + wd * xd.y;
    A0.z += wa * xa.z + wc * xc.z;  A1.z += wb * xb.z + wd * xd.z;
    A0.w += wa * xa.w + wc * xc.w;  A1.w += wb * xb.w + wd * xd.w;
  }
  for (; i < s1; ++i) {
    int sa = ssort[i];
    float4 xa = *(const float4*)&Xl[sa * 128 + l * 4];
    float pa = at.x * lrelu(xa.x + xr.x) + at.y * lrelu(xa.y + xr.y) +
               at.z * lrelu(xa.z + xr.z) + at.w * lrelu(xa.w + xr.w);
#pragma unroll
    for (int off = 1; off <= 4; off <<= 1) pa += __shfl_xor(pa, off);
    float wa = __expf(fminf(pa, 30.f));
    den0 += wa;
    A0.x += wa * xa.x; A0.y += wa * xa.y; A0.z += wa * xa.z; A0.w += wa * xa.w;
  }
  float den = den0 + den1;
  float inv = 1.f / (den + 1e-16f);
  float4 b4 = *(const float4*)&bias[l * 4];
  float4 o;
  o.x = (A0.x + A1.x) * inv + b4.x;
  o.y = (A0.y + A1.y) * inv + b4.y;
  o.z = (A0.z + A1.z) * inv + b4.z;
  o.w = (A0.w + A1.w) * inv + b4.w;
  o.x = o.x > 0.f ? o.x : __expf(o.x) - 1.f;
  o.y = o.y > 0.f ? o.y : __expf(o.y) - 1.f;
  o.z = o.z > 0.f ? o.z : __expf(o.z) - 1.f;
  o.w = o.w > 0.f ? o.w : __expf(o.w) - 1.f;
  *(float4*)&out[n * 128 + l * 4] = o;
}

// ---------------- layer 3: GEMV (128 -> 1, two weights) -------------------
__global__ __launch_bounds__(256) void gemv3(
    const float* __restrict__ H, const float* __restrict__ Wl,
    const float* __restrict__ bl, const float* __restrict__ Wr,
    const float* __restrict__ br, float* __restrict__ xl3,
    float* __restrict__ xr3, int n) {
  int wid = threadIdx.x >> 6, lane = threadIdx.x & 63;
  int node = blockIdx.x * 4 + wid;
  if (node >= n) return;
  float2 a = *(const float2*)&H[node * 128 + lane * 2];
  float2 wl2 = *(const float2*)&Wl[lane * 2];
  float2 wr2 = *(const float2*)&Wr[lane * 2];
  float sl = a.x * wl2.x + a.y * wl2.y;
  float sr = a.x * wr2.x + a.y * wr2.y;
#pragma unroll
  for (int off = 32; off; off >>= 1) {
    sl += __shfl_xor(sl, off);
    sr += __shfl_xor(sr, off);
  }
  if (lane == 0) {
    xl3[node] = sl + bl[0];
    xr3[node] = sr + br[0];
  }
}

// fused layer-3 edge phase: per-node wave, no-max softmax, wave merge
__global__ __launch_bounds__(256) void aggregate3_fused(
    const float* __restrict__ xl3, const float* __restrict__ xr3,
    const float* __restrict__ att, const int* __restrict__ ssort,
    const int* __restrict__ rowptr, const float* __restrict__ bias,
    float* __restrict__ out, int nn) {
  int wid = threadIdx.x >> 6, lane = threadIdx.x & 63;
  int n = blockIdx.x * 4 + wid;
  if (n >= nn) return;
  int s0 = rowptr[n], s1 = rowptr[n + 1];
  float xr = xr3[n];
  float a0 = att[0];
  float den = 0.f, acc = 0.f;
  for (int i = s0 + lane; i < s1; i += 64) {
    float xl = xl3[ssort[i]];
    float v = xl + xr;
    float p = a0 * (v > 0.f ? v : 0.2f * v);
    float w = __expf(fminf(p, 30.f));
    den += w;
    acc += w * xl;
  }
#pragma unroll
  for (int off = 32; off; off >>= 1) {
    den += __shfl_xor(den, off);
    acc += __shfl_xor(acc, off);
  }
  if (lane == 0) {
    float o = acc / (den + 1e-16f) + bias[0];
    out[n] = 1.f / (1.f + __expf(-o));
  }
}

extern "C" void kernel_launch(void* const* d_in, const int* in_sizes, int n_in,
                              void* d_out, int out_size, void* d_ws, size_t ws_size,
                              hipStream_t stream) {
  const float* x = (const float*)d_in[0];
  const int* ei = (const int*)d_in[1];
  const int* src = ei;
  const int* dst = ei + NE;
  const float* W_l1 = (const float*)d_in[2];
  const float* b_l1 = (const float*)d_in[3];
  const float* W_r1 = (const float*)d_in[4];
  const float* b_r1 = (const float*)d_in[5];
  const float* att1 = (const float*)d_in[6];
  const float* bias1 = (const float*)d_in[7];
  const float* W_l2 = (const float*)d_in[8];
  const float* b_l2 = (const float*)d_in[9];
  const float* W_r2 = (const float*)d_in[10];
  const float* b_r2 = (const float*)d_in[11];
  const float* att2 = (const float*)d_in[12];
  const float* bias2 = (const float*)d_in[13];
  const float* W_l3 = (const float*)d_in[14];
  const float* b_l3 = (const float*)d_in[15];
  const float* W_r3 = (const float*)d_in[16];
  const float* b_r3 = (const float*)d_in[17];
  const float* att3 = (const float*)d_in[18];
  const float* bias3 = (const float*)d_in[19];
  float* out = (float*)d_out;

  float* xl_a = (float*)d_ws;            // NN*128
  float* xr_a = xl_a + NN * 128;         // NN*128
  float* hbuf = xr_a + NN * 128;         // NN*128
  int* deg = (int*)(hbuf + NN * 128);    // NN
  int* rowptr = deg + NN;                // NN+1
  int* cursor = rowptr + NN + 1;         // NN
  int* bsum = cursor + NN;               // 256
  int* boff = bsum + 256;                // 256
  int* ssort = boff + 256;               // NE
  float* xl3 = (float*)(ssort + NE);     // NN
  float* xr3 = xl3 + NN;                 // NN

  const int NB_N = (NN + 255) / 256;     // 196
  const int NB_E = (NE + 255) / 256;     // 3125
  const int NB_G = (NN + 63) / 64;       // 782
  const int NB_A = (NN + 7) / 8;         // 6250
  const int NB_W4 = (NN + 3) / 4;        // 12500

  // ---- CSR build ----
  zero_i32<<<NB_N, 256, 0, stream>>>(deg, NN);
  hist_kernel<<<NB_E, 256, 0, stream>>>(dst, deg);
  scan_a<<<NB_N, 256, 0, stream>>>(deg, rowptr, bsum, NN);
  scan_a<<<1, 256, 0, stream>>>(bsum, boff, (int*)nullptr, NB_N);
  scan_c<<<NB_N + 1, 256, 0, stream>>>(rowptr, boff, cursor, NN);
  scatter_kernel<<<NB_E, 256, 0, stream>>>(src, dst, cursor, ssort);

  // ---- layer 1 ----
  gemm_fused<<<NB_G, 256, 0, stream>>>(x, W_l1, b_l1, W_r1, b_r1, xl_a, xr_a, NN);
  gat_aggregate_fused<<<NB_A, 256, 0, stream>>>(xl_a, xr_a, att1, ssort, rowptr, bias1, hbuf);

  // ---- layer 2 ----
  gemm_fused<<<NB_G, 256, 0, stream>>>(hbuf, W_l2, b_l2, W_r2, b_r2, xl_a, xr_a, NN);
  gat_aggregate_fused<<<NB_A, 256, 0, stream>>>(xl_a, xr_a, att2, ssort, rowptr, bias2, hbuf);

  // ---- layer 3 ----
  gemv3<<<NB_W4, 256, 0, stream>>>(hbuf, W_l3, b_l3, W_r3, b_r3, xl3, xr3, NN);
  aggregate3_fused<<<NB_W4, 256, 0, stream>>>(xl3, xr3, att3, ssort, rowptr, bias3, out, NN);
}

// Round 8
// 405.003 us; speedup vs baseline: 1.1995x; 1.1995x over previous
//
#include <hip/hip_runtime.h>
#include <hip/hip_bf16.h>
#include <math.h>

#define NN 50000
#define NE 800000

typedef __attribute__((ext_vector_type(8))) short bf16x8;
typedef __attribute__((ext_vector_type(4))) float f32x4;

__device__ __forceinline__ float lrelu(float x) { return x > 0.f ? x : 0.2f * x; }

__device__ __forceinline__ ushort f2bf(float v) {
  __hip_bfloat16 h = __float2bfloat16(v);
  return *(ushort*)&h;
}

// -------- convert fp32 activations -> bf16 (8 elems/thread) ---------------
__global__ void cvt_bf16(const float* __restrict__ in, ushort* __restrict__ out, int n8) {
  int i = blockIdx.x * 256 + threadIdx.x;
  if (i >= n8) return;
  float4 v0 = *(const float4*)&in[i * 8];
  float4 v1 = *(const float4*)&in[i * 8 + 4];
  ushort4 a, b;
  a.x = f2bf(v0.x); a.y = f2bf(v0.y); a.z = f2bf(v0.z); a.w = f2bf(v0.w);
  b.x = f2bf(v1.x); b.y = f2bf(v1.y); b.z = f2bf(v1.z); b.w = f2bf(v1.w);
  *(ushort4*)&out[i * 8] = a;
  *(ushort4*)&out[i * 8 + 4] = b;
}

// -------- pack Wl|Wr (fp32 [128][128] each) into MFMA B-frag bf16 layout ---
// Bpack[kt][col][hi][b] = W[kt*32 + hi*8 + b][col]   (col<128 -> Wl, else Wr)
__global__ void pack_w(const float* __restrict__ Wl, const float* __restrict__ Wr,
                       ushort* __restrict__ Bpack) {
  int t = blockIdx.x * 256 + threadIdx.x;   // (kt,col,hi): 4*256*4 = 4096
  if (t >= 4096) return;
  int hi = t & 3;
  int col = (t >> 2) & 255;
  int kt = t >> 10;
  const float* W = (col < 128) ? (Wl + col) : (Wr + (col - 128));
  ushort4 u0, u1;
  int k0 = kt * 32 + hi * 8;
  u0.x = f2bf(W[(k0 + 0) * 128]); u0.y = f2bf(W[(k0 + 1) * 128]);
  u0.z = f2bf(W[(k0 + 2) * 128]); u0.w = f2bf(W[(k0 + 3) * 128]);
  u1.x = f2bf(W[(k0 + 4) * 128]); u1.y = f2bf(W[(k0 + 5) * 128]);
  u1.z = f2bf(W[(k0 + 6) * 128]); u1.w = f2bf(W[(k0 + 7) * 128]);
  *(ushort4*)&Bpack[t * 8] = u0;
  *(ushort4*)&Bpack[t * 8 + 4] = u1;
}

// -------- MFMA dual GEMM: [Xl|Xr] = Abf @ [Wl|Wr] + [bl|br] ---------------
// 64 rows x 256 cols per block, 4 waves (64-col slice each), no LDS/barrier.
// mfma_f32_16x16x32_bf16: A[l&15][8*(l>>4)+i], B[8*(l>>4)+i][l&15],
// D: col=l&15, row=(l>>4)*4+v (m89-verified C/D mapping).
__global__ __launch_bounds__(256) void gemm_mfma(
    const ushort* __restrict__ Abf, const ushort* __restrict__ Bpack,
    const float* __restrict__ bl, const float* __restrict__ br,
    float* __restrict__ Xl, float* __restrict__ Xr, int n) {
  const int tid = threadIdx.x;
  const int wv = tid >> 6;
  const int l = tid & 63;
  const int lr = l & 15;
  const int hi = l >> 4;
  const int r0 = blockIdx.x * 64;

  f32x4 acc[4][4];
#pragma unroll
  for (int mi = 0; mi < 4; ++mi)
#pragma unroll
    for (int nj = 0; nj < 4; ++nj) acc[mi][nj] = (f32x4)0.f;

#pragma unroll
  for (int kt = 0; kt < 4; ++kt) {
    bf16x8 b[4], a[4];
#pragma unroll
    for (int nj = 0; nj < 4; ++nj) {
      int col = wv * 64 + nj * 16 + lr;
      b[nj] = *(const bf16x8*)&Bpack[((kt * 256 + col) * 4 + hi) * 8];
    }
#pragma unroll
    for (int mi = 0; mi < 4; ++mi) {
      int row = r0 + mi * 16 + lr;
      row = row < n ? row : n - 1;     // clamp tail reads (stores are guarded)
      a[mi] = *(const bf16x8*)&Abf[row * 128 + kt * 32 + hi * 8];
    }
#pragma unroll
    for (int mi = 0; mi < 4; ++mi)
#pragma unroll
      for (int nj = 0; nj < 4; ++nj)
        acc[mi][nj] = __builtin_amdgcn_mfma_f32_16x16x32_bf16(a[mi], b[nj], acc[mi][nj], 0, 0, 0);
  }

#pragma unroll
  for (int nj = 0; nj < 4; ++nj) {
    int col = wv * 64 + nj * 16 + lr;
    float bb = (col < 128) ? bl[col] : br[col - 128];
    float* dst = (col < 128) ? (Xl + col) : (Xr + (col - 128));
#pragma unroll
    for (int mi = 0; mi < 4; ++mi) {
#pragma unroll
      for (int v = 0; v < 4; ++v) {
        int row = r0 + mi * 16 + hi * 4 + v;
        if (row < n) dst[row * 128] = acc[mi][nj][v] + bb;
      }
    }
  }
}

// ---------------- CSR build ----------------
__global__ void zero_i32(int* p, int n) {
  int i = blockIdx.x * 256 + threadIdx.x;
  if (i < n) p[i] = 0;
}

__global__ void hist_kernel(const int* __restrict__ dst, int* __restrict__ deg) {
  int e = blockIdx.x * 256 + threadIdx.x;
  if (e < NE) atomicAdd(&deg[dst[e]], 1);
}

__global__ __launch_bounds__(256) void scan_a(const int* __restrict__ in,
                                              int* __restrict__ excl,
                                              int* __restrict__ bsum, int n) {
  int i = blockIdx.x * 256 + threadIdx.x;
  int v = (i < n) ? in[i] : 0;
  int lane = threadIdx.x & 63, wid = threadIdx.x >> 6;
  int incl = v;
#pragma unroll
  for (int off = 1; off < 64; off <<= 1) {
    int u = __shfl_up(incl, off);
    if (lane >= off) incl += u;
  }
  __shared__ int wsum[4];
  if (lane == 63) wsum[wid] = incl;
  __syncthreads();
  int wo = 0;
  for (int w = 0; w < wid; w++) wo += wsum[w];
  if (i < n) excl[i] = wo + incl - v;
  if (threadIdx.x == 255 && bsum) bsum[blockIdx.x] = wo + incl;
}

__global__ void scan_c(int* __restrict__ rowptr, const int* __restrict__ boff,
                       int* __restrict__ cursor, int n) {
  int i = blockIdx.x * 256 + threadIdx.x;
  if (i < n) {
    int v = rowptr[i] + boff[i >> 8];
    rowptr[i] = v;
    cursor[i] = v;
  } else if (i == n) {
    rowptr[n] = NE;
  }
}

__global__ void scatter_kernel(const int* __restrict__ src, const int* __restrict__ dst,
                               int* __restrict__ cursor, int* __restrict__ ssort) {
  int e = blockIdx.x * 256 + threadIdx.x;
  if (e >= NE) return;
  int p = atomicAdd(&cursor[dst[e]], 1);
  ssort[p] = src[e];
}

// ------- fused: logits + segment-softmax + aggregate + bias + ELU ---------
// also writes bf16 copy of the output (next layer's MFMA input)
__global__ __launch_bounds__(256) void gat_aggregate_fused(
    const float* __restrict__ Xl, const float* __restrict__ Xr,
    const float* __restrict__ att, const int* __restrict__ ssort,
    const int* __restrict__ rowptr, const float* __restrict__ bias,
    float* __restrict__ out, ushort* __restrict__ outb) {
  int slot = threadIdx.x >> 5;
  int l = threadIdx.x & 31;
  int n = blockIdx.x * 8 + slot;
  if (n >= NN) return;
  int s0 = rowptr[n], s1 = rowptr[n + 1];
  float4 xr = *(const float4*)&Xr[n * 128 + l * 4];
  float4 at = *(const float4*)&att[l * 4];

  float den0 = 0.f, den1 = 0.f;
  float4 A0 = make_float4(0.f, 0.f, 0.f, 0.f);
  float4 A1 = make_float4(0.f, 0.f, 0.f, 0.f);

  int i = s0;
  for (; i + 4 <= s1; i += 4) {
    int sa = ssort[i], sb = ssort[i + 1], sc = ssort[i + 2], sd = ssort[i + 3];
    float4 xa = *(const float4*)&Xl[sa * 128 + l * 4];
    float4 xb = *(const float4*)&Xl[sb * 128 + l * 4];
    float4 xc = *(const float4*)&Xl[sc * 128 + l * 4];
    float4 xd = *(const float4*)&Xl[sd * 128 + l * 4];
    float pa = at.x * lrelu(xa.x + xr.x) + at.y * lrelu(xa.y + xr.y) +
               at.z * lrelu(xa.z + xr.z) + at.w * lrelu(xa.w + xr.w);
    float pb = at.x * lrelu(xb.x + xr.x) + at.y * lrelu(xb.y + xr.y) +
               at.z * lrelu(xb.z + xr.z) + at.w * lrelu(xb.w + xr.w);
    float pc = at.x * lrelu(xc.x + xr.x) + at.y * lrelu(xc.y + xr.y) +
               at.z * lrelu(xc.z + xr.z) + at.w * lrelu(xc.w + xr.w);
    float pd = at.x * lrelu(xd.x + xr.x) + at.y * lrelu(xd.y + xr.y) +
               at.z * lrelu(xd.z + xr.z) + at.w * lrelu(xd.w + xr.w);
#pragma unroll
    for (int off = 1; off <= 4; off <<= 1) {
      pa += __shfl_xor(pa, off);
      pb += __shfl_xor(pb, off);
      pc += __shfl_xor(pc, off);
      pd += __shfl_xor(pd, off);
    }
    float wa = __expf(fminf(pa, 30.f));
    float wb = __expf(fminf(pb, 30.f));
    float wc = __expf(fminf(pc, 30.f));
    float wd = __expf(fminf(pd, 30.f));
    den0 += wa + wc;
    den1 += wb + wd;
    A0.x += wa * xa.x + wc * xc.x;  A1.x += wb * xb.x + wd * xd.x;
    A0.y += wa * xa.y + wc * xc.y;  A1.y += wb * xb.y + wd * xd.y;
    A0.z += wa * xa.z + wc * xc.z;  A1.z += wb * xb.z + wd * xd.z;
    A0.w += wa * xa.w + wc * xc.w;  A1.w += wb * xb.w + wd * xd.w;
  }
  for (; i < s1; ++i) {
    int sa = ssort[i];
    float4 xa = *(const float4*)&Xl[sa * 128 + l * 4];
    float pa = at.x * lrelu(xa.x + xr.x) + at.y * lrelu(xa.y + xr.y) +
               at.z * lrelu(xa.z + xr.z) + at.w * lrelu(xa.w + xr.w);
#pragma unroll
    for (int off = 1; off <= 4; off <<= 1) pa += __shfl_xor(pa, off);
    float wa = __expf(fminf(pa, 30.f));
    den0 += wa;
    A0.x += wa * xa.x; A0.y += wa * xa.y; A0.z += wa * xa.z; A0.w += wa * xa.w;
  }
  float den = den0 + den1;
  float inv = 1.f / (den + 1e-16f);
  float4 b4 = *(const float4*)&bias[l * 4];
  float4 o;
  o.x = (A0.x + A1.x) * inv + b4.x;
  o.y = (A0.y + A1.y) * inv + b4.y;
  o.z = (A0.z + A1.z) * inv + b4.z;
  o.w = (A0.w + A1.w) * inv + b4.w;
  o.x = o.x > 0.f ? o.x : __expf(o.x) - 1.f;
  o.y = o.y > 0.f ? o.y : __expf(o.y) - 1.f;
  o.z = o.z > 0.f ? o.z : __expf(o.z) - 1.f;
  o.w = o.w > 0.f ? o.w : __expf(o.w) - 1.f;
  *(float4*)&out[n * 128 + l * 4] = o;
  ushort4 ub;
  ub.x = f2bf(o.x); ub.y = f2bf(o.y); ub.z = f2bf(o.z); ub.w = f2bf(o.w);
  *(ushort4*)&outb[n * 128 + l * 4] = ub;
}

// ---------------- layer 3: GEMV (128 -> 1, two weights) -------------------
__global__ __launch_bounds__(256) void gemv3(
    const float* __restrict__ H, const float* __restrict__ Wl,
    const float* __restrict__ bl, const float* __restrict__ Wr,
    const float* __restrict__ br, float* __restrict__ xl3,
    float* __restrict__ xr3, int n) {
  int wid = threadIdx.x >> 6, lane = threadIdx.x & 63;
  int node = blockIdx.x * 4 + wid;
  if (node >= n) return;
  float2 a = *(const float2*)&H[node * 128 + lane * 2];
  float2 wl2 = *(const float2*)&Wl[lane * 2];
  float2 wr2 = *(const float2*)&Wr[lane * 2];
  float sl = a.x * wl2.x + a.y * wl2.y;
  float sr = a.x * wr2.x + a.y * wr2.y;
#pragma unroll
  for (int off = 32; off; off >>= 1) {
    sl += __shfl_xor(sl, off);
    sr += __shfl_xor(sr, off);
  }
  if (lane == 0) {
    xl3[node] = sl + bl[0];
    xr3[node] = sr + br[0];
  }
}

// fused layer-3 edge phase: per-node wave, no-max softmax, wave merge
__global__ __launch_bounds__(256) void aggregate3_fused(
    const float* __restrict__ xl3, const float* __restrict__ xr3,
    const float* __restrict__ att, const int* __restrict__ ssort,
    const int* __restrict__ rowptr, const float* __restrict__ bias,
    float* __restrict__ out, int nn) {
  int wid = threadIdx.x >> 6, lane = threadIdx.x & 63;
  int n = blockIdx.x * 4 + wid;
  if (n >= nn) return;
  int s0 = rowptr[n], s1 = rowptr[n + 1];
  float xr = xr3[n];
  float a0 = att[0];
  float den = 0.f, acc = 0.f;
  for (int i = s0 + lane; i < s1; i += 64) {
    float xl = xl3[ssort[i]];
    float v = xl + xr;
    float p = a0 * (v > 0.f ? v : 0.2f * v);
    float w = __expf(fminf(p, 30.f));
    den += w;
    acc += w * xl;
  }
#pragma unroll
  for (int off = 32; off; off >>= 1) {
    den += __shfl_xor(den, off);
    acc += __shfl_xor(acc, off);
  }
  if (lane == 0) {
    float o = acc / (den + 1e-16f) + bias[0];
    out[n] = 1.f / (1.f + __expf(-o));
  }
}

extern "C" void kernel_launch(void* const* d_in, const int* in_sizes, int n_in,
                              void* d_out, int out_size, void* d_ws, size_t ws_size,
                              hipStream_t stream) {
  const float* x = (const float*)d_in[0];
  const int* ei = (const int*)d_in[1];
  const int* src = ei;
  const int* dst = ei + NE;
  const float* W_l1 = (const float*)d_in[2];
  const float* b_l1 = (const float*)d_in[3];
  const float* W_r1 = (const float*)d_in[4];
  const float* b_r1 = (const float*)d_in[5];
  const float* att1 = (const float*)d_in[6];
  const float* bias1 = (const float*)d_in[7];
  const float* W_l2 = (const float*)d_in[8];
  const float* b_l2 = (const float*)d_in[9];
  const float* W_r2 = (const float*)d_in[10];
  const float* b_r2 = (const float*)d_in[11];
  const float* att2 = (const float*)d_in[12];
  const float* bias2 = (const float*)d_in[13];
  const float* W_l3 = (const float*)d_in[14];
  const float* b_l3 = (const float*)d_in[15];
  const float* W_r3 = (const float*)d_in[16];
  const float* b_r3 = (const float*)d_in[17];
  const float* att3 = (const float*)d_in[18];
  const float* bias3 = (const float*)d_in[19];
  float* out = (float*)d_out;

  float* xl_a = (float*)d_ws;            // NN*128 f32
  float* xr_a = xl_a + NN * 128;         // NN*128 f32
  float* hbuf = xr_a + NN * 128;         // NN*128 f32
  ushort* xbb = (ushort*)(hbuf + NN * 128);  // NN*128 bf16 (activation input)
  ushort* bpack = xbb + NN * 128;        // 32768 bf16 packed weights
  int* deg = (int*)(bpack + 32768);      // NN
  int* rowptr = deg + NN;                // NN+1
  int* cursor = rowptr + NN + 1;         // NN
  int* bsum = cursor + NN;               // 256
  int* boff = bsum + 256;                // 256
  int* ssort = boff + 256;               // NE
  float* xl3 = (float*)(ssort + NE);     // NN
  float* xr3 = xl3 + NN;                 // NN

  const int NB_N = (NN + 255) / 256;     // 196
  const int NB_E = (NE + 255) / 256;     // 3125
  const int NB_G = (NN + 63) / 64;       // 782
  const int NB_A = (NN + 7) / 8;         // 6250
  const int NB_W4 = (NN + 3) / 4;        // 12500
  const int NB_C = (NN * 128 / 8 + 255) / 256;  // 3125 cvt blocks

  // ---- CSR build ----
  zero_i32<<<NB_N, 256, 0, stream>>>(deg, NN);
  hist_kernel<<<NB_E, 256, 0, stream>>>(dst, deg);
  scan_a<<<NB_N, 256, 0, stream>>>(deg, rowptr, bsum, NN);
  scan_a<<<1, 256, 0, stream>>>(bsum, boff, (int*)nullptr, NB_N);
  scan_c<<<NB_N + 1, 256, 0, stream>>>(rowptr, boff, cursor, NN);
  scatter_kernel<<<NB_E, 256, 0, stream>>>(src, dst, cursor, ssort);

  // ---- layer 1 ----
  cvt_bf16<<<NB_C, 256, 0, stream>>>(x, xbb, NN * 128 / 8);
  pack_w<<<16, 256, 0, stream>>>(W_l1, W_r1, bpack);
  gemm_mfma<<<NB_G, 256, 0, stream>>>(xbb, bpack, b_l1, b_r1, xl_a, xr_a, NN);
  gat_aggregate_fused<<<NB_A, 256, 0, stream>>>(xl_a, xr_a, att1, ssort, rowptr, bias1, hbuf, xbb);

  // ---- layer 2 ----
  pack_w<<<16, 256, 0, stream>>>(W_l2, W_r2, bpack);
  gemm_mfma<<<NB_G, 256, 0, stream>>>(xbb, bpack, b_l2, b_r2, xl_a, xr_a, NN);
  gat_aggregate_fused<<<NB_A, 256, 0, stream>>>(xl_a, xr_a, att2, ssort, rowptr, bias2, hbuf, xbb);

  // ---- layer 3 ----
  gemv3<<<NB_W4, 256, 0, stream>>>(hbuf, W_l3, b_l3, W_r3, b_r3, xl3, xr3, NN);
  aggregate3_fused<<<NB_W4, 256, 0, stream>>>(xl3, xr3, att3, ssort, rowptr, bias3, out, NN);
}

// Round 9
// 368.852 us; speedup vs baseline: 1.3171x; 1.0980x over previous
//
#include <hip/hip_runtime.h>
#include <hip/hip_bf16.h>
#include <math.h>

#define NN 50000
#define NE 800000

typedef __attribute__((ext_vector_type(8))) short bf16x8;
typedef __attribute__((ext_vector_type(4))) float f32x4;

__device__ __forceinline__ float lrelu(float x) { return x > 0.f ? x : 0.2f * x; }

__device__ __forceinline__ ushort f2bf(float v) {
  __hip_bfloat16 h = __float2bfloat16(v);
  return *(ushort*)&h;
}
__device__ __forceinline__ float bf2f(ushort u) {
  return __uint_as_float(((unsigned int)u) << 16);
}

// -------- convert fp32 activations -> bf16 (8 elems/thread) ---------------
__global__ void cvt_bf16(const float* __restrict__ in, ushort* __restrict__ out, int n8) {
  int i = blockIdx.x * 256 + threadIdx.x;
  if (i >= n8) return;
  float4 v0 = *(const float4*)&in[i * 8];
  float4 v1 = *(const float4*)&in[i * 8 + 4];
  ushort4 a, b;
  a.x = f2bf(v0.x); a.y = f2bf(v0.y); a.z = f2bf(v0.z); a.w = f2bf(v0.w);
  b.x = f2bf(v1.x); b.y = f2bf(v1.y); b.z = f2bf(v1.z); b.w = f2bf(v1.w);
  *(ushort4*)&out[i * 8] = a;
  *(ushort4*)&out[i * 8 + 4] = b;
}

// -------- pack Wl|Wr (fp32 [128][128] each) into MFMA B-frag bf16 layout ---
// Bpack[kt][col][hi][b] = W[kt*32 + hi*8 + b][col]
__global__ void pack_w(const float* __restrict__ Wl, const float* __restrict__ Wr,
                       ushort* __restrict__ Bpack) {
  int t = blockIdx.x * 256 + threadIdx.x;   // (kt,col,hi): 4*256*4 = 4096
  if (t >= 4096) return;
  int hi = t & 3;
  int col = (t >> 2) & 255;
  int kt = t >> 10;
  const float* W = (col < 128) ? (Wl + col) : (Wr + (col - 128));
  ushort4 u0, u1;
  int k0 = kt * 32 + hi * 8;
  u0.x = f2bf(W[(k0 + 0) * 128]); u0.y = f2bf(W[(k0 + 1) * 128]);
  u0.z = f2bf(W[(k0 + 2) * 128]); u0.w = f2bf(W[(k0 + 3) * 128]);
  u1.x = f2bf(W[(k0 + 4) * 128]); u1.y = f2bf(W[(k0 + 5) * 128]);
  u1.z = f2bf(W[(k0 + 6) * 128]); u1.w = f2bf(W[(k0 + 7) * 128]);
  *(ushort4*)&Bpack[t * 8] = u0;
  *(ushort4*)&Bpack[t * 8 + 4] = u1;
}

// -------- MFMA dual GEMM: [Xl|Xr](bf16) = Abf @ [Wl|Wr] + [bl|br] ---------
// 64 rows x 256 cols per block, 4 waves (64-col slice each), no LDS/barrier.
__global__ __launch_bounds__(256) void gemm_mfma(
    const ushort* __restrict__ Abf, const ushort* __restrict__ Bpack,
    const float* __restrict__ bl, const float* __restrict__ br,
    ushort* __restrict__ Xl, ushort* __restrict__ Xr, int n) {
  const int tid = threadIdx.x;
  const int wv = tid >> 6;
  const int l = tid & 63;
  const int lr = l & 15;
  const int hi = l >> 4;
  const int r0 = blockIdx.x * 64;

  f32x4 acc[4][4];
#pragma unroll
  for (int mi = 0; mi < 4; ++mi)
#pragma unroll
    for (int nj = 0; nj < 4; ++nj) acc[mi][nj] = (f32x4)0.f;

#pragma unroll
  for (int kt = 0; kt < 4; ++kt) {
    bf16x8 b[4], a[4];
#pragma unroll
    for (int nj = 0; nj < 4; ++nj) {
      int col = wv * 64 + nj * 16 + lr;
      b[nj] = *(const bf16x8*)&Bpack[((kt * 256 + col) * 4 + hi) * 8];
    }
#pragma unroll
    for (int mi = 0; mi < 4; ++mi) {
      int row = r0 + mi * 16 + lr;
      row = row < n ? row : n - 1;     // clamp tail reads (stores guarded)
      a[mi] = *(const bf16x8*)&Abf[row * 128 + kt * 32 + hi * 8];
    }
#pragma unroll
    for (int mi = 0; mi < 4; ++mi)
#pragma unroll
      for (int nj = 0; nj < 4; ++nj)
        acc[mi][nj] = __builtin_amdgcn_mfma_f32_16x16x32_bf16(a[mi], b[nj], acc[mi][nj], 0, 0, 0);
  }

#pragma unroll
  for (int nj = 0; nj < 4; ++nj) {
    int col = wv * 64 + nj * 16 + lr;
    float bb = (col < 128) ? bl[col] : br[col - 128];
    ushort* dst = (col < 128) ? (Xl + col) : (Xr + (col - 128));
#pragma unroll
    for (int mi = 0; mi < 4; ++mi) {
#pragma unroll
      for (int v = 0; v < 4; ++v) {
        int row = r0 + mi * 16 + hi * 4 + v;
        if (row < n) dst[row * 128] = f2bf(acc[mi][nj][v] + bb);
      }
    }
  }
}

// ---------------- CSR build ----------------
__global__ void zero_i32(int* p, int n) {
  int i = blockIdx.x * 256 + threadIdx.x;
  if (i < n) p[i] = 0;
}

__global__ void hist_kernel(const int* __restrict__ dst, int* __restrict__ deg) {
  int e = blockIdx.x * 256 + threadIdx.x;
  if (e < NE) atomicAdd(&deg[dst[e]], 1);
}

__global__ __launch_bounds__(256) void scan_a(const int* __restrict__ in,
                                              int* __restrict__ excl,
                                              int* __restrict__ bsum, int n) {
  int i = blockIdx.x * 256 + threadIdx.x;
  int v = (i < n) ? in[i] : 0;
  int lane = threadIdx.x & 63, wid = threadIdx.x >> 6;
  int incl = v;
#pragma unroll
  for (int off = 1; off < 64; off <<= 1) {
    int u = __shfl_up(incl, off);
    if (lane >= off) incl += u;
  }
  __shared__ int wsum[4];
  if (lane == 63) wsum[wid] = incl;
  __syncthreads();
  int wo = 0;
  for (int w = 0; w < wid; w++) wo += wsum[w];
  if (i < n) excl[i] = wo + incl - v;
  if (threadIdx.x == 255 && bsum) bsum[blockIdx.x] = wo + incl;
}

__global__ void scan_c(int* __restrict__ rowptr, const int* __restrict__ boff,
                       int* __restrict__ cursor, int n) {
  int i = blockIdx.x * 256 + threadIdx.x;
  if (i < n) {
    int v = rowptr[i] + boff[i >> 8];
    rowptr[i] = v;
    cursor[i] = v;
  } else if (i == n) {
    rowptr[n] = NE;
  }
}

__global__ void scatter_kernel(const int* __restrict__ src, const int* __restrict__ dst,
                               int* __restrict__ cursor, int* __restrict__ ssort) {
  int e = blockIdx.x * 256 + threadIdx.x;
  if (e >= NE) return;
  int p = atomicAdd(&cursor[dst[e]], 1);
  ssort[p] = src[e];
}

// ------- fused: logits + segment-softmax + aggregate + bias + ELU ---------
// bf16 gather table. MODE 0: write bf16 activation (next layer input).
// MODE 1: fuse layer-3 GEMV into epilogue -> write xl3/xr3 scalars.
template <int MODE>
__global__ __launch_bounds__(256) void gat_aggregate(
    const ushort* __restrict__ Xl, const ushort* __restrict__ Xr,
    const float* __restrict__ att, const int* __restrict__ ssort,
    const int* __restrict__ rowptr, const float* __restrict__ bias,
    ushort* __restrict__ outb,
    const float* __restrict__ Wl3, const float* __restrict__ Wr3,
    const float* __restrict__ bl3, const float* __restrict__ br3,
    float* __restrict__ xl3, float* __restrict__ xr3) {
  int slot = threadIdx.x >> 5;
  int l = threadIdx.x & 31;
  int n = blockIdx.x * 8 + slot;
  if (n >= NN) return;
  int s0 = rowptr[n], s1 = rowptr[n + 1];
  ushort4 xru = *(const ushort4*)&Xr[n * 128 + l * 4];
  float4 xr = make_float4(bf2f(xru.x), bf2f(xru.y), bf2f(xru.z), bf2f(xru.w));
  float4 at = *(const float4*)&att[l * 4];

  float den0 = 0.f, den1 = 0.f;
  float4 A0 = make_float4(0.f, 0.f, 0.f, 0.f);
  float4 A1 = make_float4(0.f, 0.f, 0.f, 0.f);

  int i = s0;
  for (; i + 4 <= s1; i += 4) {
    int sa = ssort[i], sb = ssort[i + 1], sc = ssort[i + 2], sd = ssort[i + 3];
    ushort4 ua = *(const ushort4*)&Xl[sa * 128 + l * 4];
    ushort4 ub = *(const ushort4*)&Xl[sb * 128 + l * 4];
    ushort4 uc = *(const ushort4*)&Xl[sc * 128 + l * 4];
    ushort4 ud = *(const ushort4*)&Xl[sd * 128 + l * 4];
    float4 xa = make_float4(bf2f(ua.x), bf2f(ua.y), bf2f(ua.z), bf2f(ua.w));
    float4 xb = make_float4(bf2f(ub.x), bf2f(ub.y), bf2f(ub.z), bf2f(ub.w));
    float4 xc = make_float4(bf2f(uc.x), bf2f(uc.y), bf2f(uc.z), bf2f(uc.w));
    float4 xd = make_float4(bf2f(ud.x), bf2f(ud.y), bf2f(ud.z), bf2f(ud.w));
    float pa = at.x * lrelu(xa.x + xr.x) + at.y * lrelu(xa.y + xr.y) +
               at.z * lrelu(xa.z + xr.z) + at.w * lrelu(xa.w + xr.w);
    float pb = at.x * lrelu(xb.x + xr.x) + at.y * lrelu(xb.y + xr.y) +
               at.z * lrelu(xb.z + xr.z) + at.w * lrelu(xb.w + xr.w);
    float pc = at.x * lrelu(xc.x + xr.x) + at.y * lrelu(xc.y + xr.y) +
               at.z * lrelu(xc.z + xr.z) + at.w * lrelu(xc.w + xr.w);
    float pd = at.x * lrelu(xd.x + xr.x) + at.y * lrelu(xd.y + xr.y) +
               at.z * lrelu(xd.z + xr.z) + at.w * lrelu(xd.w + xr.w);
#pragma unroll
    for (int off = 1; off <= 4; off <<= 1) {
      pa += __shfl_xor(pa, off);
      pb += __shfl_xor(pb, off);
      pc += __shfl_xor(pc, off);
      pd += __shfl_xor(pd, off);
    }
    float wa = __expf(fminf(pa, 30.f));
    float wb = __expf(fminf(pb, 30.f));
    float wc = __expf(fminf(pc, 30.f));
    float wd = __expf(fminf(pd, 30.f));
    den0 += wa + wc;
    den1 += wb + wd;
    A0.x += wa * xa.x + wc * xc.x;  A1.x += wb * xb.x + wd * xd.x;
    A0.y += wa * xa.y + wc * xc.y;  A1.y += wb * xb.y + wd * xd.y;
    A0.z += wa * xa.z + wc * xc.z;  A1.z += wb * xb.z + wd * xd.z;
    A0.w += wa * xa.w + wc * xc.w;  A1.w += wb * xb.w + wd * xd.w;
  }
  for (; i < s1; ++i) {
    int sa = ssort[i];
    ushort4 ua = *(const ushort4*)&Xl[sa * 128 + l * 4];
    float4 xa = make_float4(bf2f(ua.x), bf2f(ua.y), bf2f(ua.z), bf2f(ua.w));
    float pa = at.x * lrelu(xa.x + xr.x) + at.y * lrelu(xa.y + xr.y) +
               at.z * lrelu(xa.z + xr.z) + at.w * lrelu(xa.w + xr.w);
#pragma unroll
    for (int off = 1; off <= 4; off <<= 1) pa += __shfl_xor(pa, off);
    float wa = __expf(fminf(pa, 30.f));
    den0 += wa;
    A0.x += wa * xa.x; A0.y += wa * xa.y; A0.z += wa * xa.z; A0.w += wa * xa.w;
  }
  float den = den0 + den1;
  float inv = 1.f / (den + 1e-16f);
  float4 b4 = *(const float4*)&bias[l * 4];
  float4 o;
  o.x = (A0.x + A1.x) * inv + b4.x;
  o.y = (A0.y + A1.y) * inv + b4.y;
  o.z = (A0.z + A1.z) * inv + b4.z;
  o.w = (A0.w + A1.w) * inv + b4.w;
  o.x = o.x > 0.f ? o.x : __expf(o.x) - 1.f;
  o.y = o.y > 0.f ? o.y : __expf(o.y) - 1.f;
  o.z = o.z > 0.f ? o.z : __expf(o.z) - 1.f;
  o.w = o.w > 0.f ? o.w : __expf(o.w) - 1.f;
  if (MODE == 0) {
    ushort4 ub;
    ub.x = f2bf(o.x); ub.y = f2bf(o.y); ub.z = f2bf(o.z); ub.w = f2bf(o.w);
    *(ushort4*)&outb[n * 128 + l * 4] = ub;
  } else {
    float4 wl = *(const float4*)&Wl3[l * 4];
    float4 wr = *(const float4*)&Wr3[l * 4];
    float sl = o.x * wl.x + o.y * wl.y + o.z * wl.z + o.w * wl.w;
    float sr = o.x * wr.x + o.y * wr.y + o.z * wr.z + o.w * wr.w;
#pragma unroll
    for (int off = 1; off <= 16; off <<= 1) {
      sl += __shfl_xor(sl, off);
      sr += __shfl_xor(sr, off);
    }
    if (l == 0) {
      xl3[n] = sl + bl3[0];
      xr3[n] = sr + br3[0];
    }
  }
}

// fused layer-3 edge phase: per-node wave, no-max softmax, wave merge
__global__ __launch_bounds__(256) void aggregate3_fused(
    const float* __restrict__ xl3, const float* __restrict__ xr3,
    const float* __restrict__ att, const int* __restrict__ ssort,
    const int* __restrict__ rowptr, const float* __restrict__ bias,
    float* __restrict__ out, int nn) {
  int wid = threadIdx.x >> 6, lane = threadIdx.x & 63;
  int n = blockIdx.x * 4 + wid;
  if (n >= nn) return;
  int s0 = rowptr[n], s1 = rowptr[n + 1];
  float xr = xr3[n];
  float a0 = att[0];
  float den = 0.f, acc = 0.f;
  for (int i = s0 + lane; i < s1; i += 64) {
    float xl = xl3[ssort[i]];
    float v = xl + xr;
    float p = a0 * (v > 0.f ? v : 0.2f * v);
    float w = __expf(fminf(p, 30.f));
    den += w;
    acc += w * xl;
  }
#pragma unroll
  for (int off = 32; off; off >>= 1) {
    den += __shfl_xor(den, off);
    acc += __shfl_xor(acc, off);
  }
  if (lane == 0) {
    float o = acc / (den + 1e-16f) + bias[0];
    out[n] = 1.f / (1.f + __expf(-o));
  }
}

extern "C" void kernel_launch(void* const* d_in, const int* in_sizes, int n_in,
                              void* d_out, int out_size, void* d_ws, size_t ws_size,
                              hipStream_t stream) {
  const float* x = (const float*)d_in[0];
  const int* ei = (const int*)d_in[1];
  const int* src = ei;
  const int* dst = ei + NE;
  const float* W_l1 = (const float*)d_in[2];
  const float* b_l1 = (const float*)d_in[3];
  const float* W_r1 = (const float*)d_in[4];
  const float* b_r1 = (const float*)d_in[5];
  const float* att1 = (const float*)d_in[6];
  const float* bias1 = (const float*)d_in[7];
  const float* W_l2 = (const float*)d_in[8];
  const float* b_l2 = (const float*)d_in[9];
  const float* W_r2 = (const float*)d_in[10];
  const float* b_r2 = (const float*)d_in[11];
  const float* att2 = (const float*)d_in[12];
  const float* bias2 = (const float*)d_in[13];
  const float* W_l3 = (const float*)d_in[14];
  const float* b_l3 = (const float*)d_in[15];
  const float* W_r3 = (const float*)d_in[16];
  const float* b_r3 = (const float*)d_in[17];
  const float* att3 = (const float*)d_in[18];
  const float* bias3 = (const float*)d_in[19];
  float* out = (float*)d_out;

  ushort* xbb = (ushort*)d_ws;           // NN*128 bf16 (gemm A input)
  ushort* xl_b = xbb + NN * 128;         // NN*128 bf16
  ushort* xr_b = xl_b + NN * 128;        // NN*128 bf16
  ushort* bpack = xr_b + NN * 128;       // 32768 bf16 packed weights
  int* deg = (int*)(bpack + 32768);      // NN
  int* rowptr = deg + NN;                // NN+1
  int* cursor = rowptr + NN + 1;         // NN
  int* bsum = cursor + NN;               // 256
  int* boff = bsum + 256;                // 256
  int* ssort = boff + 256;               // NE
  float* xl3 = (float*)(ssort + NE);     // NN
  float* xr3 = xl3 + NN;                 // NN

  const int NB_N = (NN + 255) / 256;     // 196
  const int NB_E = (NE + 255) / 256;     // 3125
  const int NB_G = (NN + 63) / 64;       // 782
  const int NB_A = (NN + 7) / 8;         // 6250
  const int NB_W4 = (NN + 3) / 4;        // 12500
  const int NB_C = (NN * 128 / 8 + 255) / 256;  // 3125

  // ---- CSR build ----
  zero_i32<<<NB_N, 256, 0, stream>>>(deg, NN);
  hist_kernel<<<NB_E, 256, 0, stream>>>(dst, deg);
  scan_a<<<NB_N, 256, 0, stream>>>(deg, rowptr, bsum, NN);
  scan_a<<<1, 256, 0, stream>>>(bsum, boff, (int*)nullptr, NB_N);
  scan_c<<<NB_N + 1, 256, 0, stream>>>(rowptr, boff, cursor, NN);
  scatter_kernel<<<NB_E, 256, 0, stream>>>(src, dst, cursor, ssort);

  // ---- layer 1 ----
  cvt_bf16<<<NB_C, 256, 0, stream>>>(x, xbb, NN * 128 / 8);
  pack_w<<<16, 256, 0, stream>>>(W_l1, W_r1, bpack);
  gemm_mfma<<<NB_G, 256, 0, stream>>>(xbb, bpack, b_l1, b_r1, xl_b, xr_b, NN);
  gat_aggregate<0><<<NB_A, 256, 0, stream>>>(xl_b, xr_b, att1, ssort, rowptr, bias1,
                                             xbb, nullptr, nullptr, nullptr, nullptr,
                                             nullptr, nullptr);

  // ---- layer 2 (+ fused layer-3 GEMV epilogue) ----
  pack_w<<<16, 256, 0, stream>>>(W_l2, W_r2, bpack);
  gemm_mfma<<<NB_G, 256, 0, stream>>>(xbb, bpack, b_l2, b_r2, xl_b, xr_b, NN);
  gat_aggregate<1><<<NB_A, 256, 0, stream>>>(xl_b, xr_b, att2, ssort, rowptr, bias2,
                                             nullptr, W_l3, W_r3, b_l3, b_r3,
                                             xl3, xr3);

  // ---- layer 3 edge phase ----
  aggregate3_fused<<<NB_W4, 256, 0, stream>>>(xl3, xr3, att3, ssort, rowptr, bias3, out, NN);
}

// Round 11
// 343.923 us; speedup vs baseline: 1.4126x; 1.0725x over previous
//
#include <hip/hip_runtime.h>
#include <hip/hip_bf16.h>
#include <math.h>

#define NN 50000
#define NE 800000
#define NBUK 391      // ceil(NN/128)
#define BNODES 128

typedef __attribute__((ext_vector_type(8))) short bf16x8;
typedef __attribute__((ext_vector_type(4))) float f32x4;

__device__ __forceinline__ float lrelu(float x) { return x > 0.f ? x : 0.2f * x; }

__device__ __forceinline__ ushort f2bf(float v) {
  __hip_bfloat16 h = __float2bfloat16(v);
  return *(ushort*)&h;
}
__device__ __forceinline__ float bf2f(ushort u) {
  return __uint_as_float(((unsigned int)u) << 16);
}

// -------- convert fp32 activations -> bf16 (8 elems/thread) ---------------
__global__ void cvt_bf16(const float* __restrict__ in, ushort* __restrict__ out, int n8) {
  int i = blockIdx.x * 256 + threadIdx.x;
  if (i >= n8) return;
  float4 v0 = *(const float4*)&in[i * 8];
  float4 v1 = *(const float4*)&in[i * 8 + 4];
  ushort4 a, b;
  a.x = f2bf(v0.x); a.y = f2bf(v0.y); a.z = f2bf(v0.z); a.w = f2bf(v0.w);
  b.x = f2bf(v1.x); b.y = f2bf(v1.y); b.z = f2bf(v1.z); b.w = f2bf(v1.w);
  *(ushort4*)&out[i * 8] = a;
  *(ushort4*)&out[i * 8 + 4] = b;
}

// -------- pack Wl|Wr (fp32 [128][128] each) into MFMA B-frag bf16 layout ---
__global__ void pack_w(const float* __restrict__ Wl, const float* __restrict__ Wr,
                       ushort* __restrict__ Bpack) {
  int t = blockIdx.x * 256 + threadIdx.x;   // (kt,col,hi): 4*256*4 = 4096
  if (t >= 4096) return;
  int hi = t & 3;
  int col = (t >> 2) & 255;
  int kt = t >> 10;
  const float* W = (col < 128) ? (Wl + col) : (Wr + (col - 128));
  ushort4 u0, u1;
  int k0 = kt * 32 + hi * 8;
  u0.x = f2bf(W[(k0 + 0) * 128]); u0.y = f2bf(W[(k0 + 1) * 128]);
  u0.z = f2bf(W[(k0 + 2) * 128]); u0.w = f2bf(W[(k0 + 3) * 128]);
  u1.x = f2bf(W[(k0 + 4) * 128]); u1.y = f2bf(W[(k0 + 5) * 128]);
  u1.z = f2bf(W[(k0 + 6) * 128]); u1.w = f2bf(W[(k0 + 7) * 128]);
  *(ushort4*)&Bpack[t * 8] = u0;
  *(ushort4*)&Bpack[t * 8 + 4] = u1;
}

// -------- MFMA dual GEMM: [Xl|Xr](bf16) = Abf @ [Wl|Wr] + [bl|br] ---------
__global__ __launch_bounds__(256) void gemm_mfma(
    const ushort* __restrict__ Abf, const ushort* __restrict__ Bpack,
    const float* __restrict__ bl, const float* __restrict__ br,
    ushort* __restrict__ Xl, ushort* __restrict__ Xr, int n) {
  const int tid = threadIdx.x;
  const int wv = tid >> 6;
  const int l = tid & 63;
  const int lr = l & 15;
  const int hi = l >> 4;
  const int r0 = blockIdx.x * 64;

  f32x4 acc[4][4];
#pragma unroll
  for (int mi = 0; mi < 4; ++mi)
#pragma unroll
    for (int nj = 0; nj < 4; ++nj) acc[mi][nj] = (f32x4)0.f;

#pragma unroll
  for (int kt = 0; kt < 4; ++kt) {
    bf16x8 b[4], a[4];
#pragma unroll
    for (int nj = 0; nj < 4; ++nj) {
      int col = wv * 64 + nj * 16 + lr;
      b[nj] = *(const bf16x8*)&Bpack[((kt * 256 + col) * 4 + hi) * 8];
    }
#pragma unroll
    for (int mi = 0; mi < 4; ++mi) {
      int row = r0 + mi * 16 + lr;
      row = row < n ? row : n - 1;     // clamp tail reads (stores guarded)
      a[mi] = *(const bf16x8*)&Abf[row * 128 + kt * 32 + hi * 8];
    }
#pragma unroll
    for (int mi = 0; mi < 4; ++mi)
#pragma unroll
      for (int nj = 0; nj < 4; ++nj)
        acc[mi][nj] = __builtin_amdgcn_mfma_f32_16x16x32_bf16(a[mi], b[nj], acc[mi][nj], 0, 0, 0);
  }

#pragma unroll
  for (int nj = 0; nj < 4; ++nj) {
    int col = wv * 64 + nj * 16 + lr;
    float bb = (col < 128) ? bl[col] : br[col - 128];
    ushort* dst = (col < 128) ? (Xl + col) : (Xr + (col - 128));
#pragma unroll
    for (int mi = 0; mi < 4; ++mi) {
#pragma unroll
      for (int v = 0; v < 4; ++v) {
        int row = r0 + mi * 16 + hi * 4 + v;
        if (row < n) dst[row * 128] = f2bf(acc[mi][nj][v] + bb);
      }
    }
  }
}

// ---------------- CSR build ----------------
__global__ void zero_i32(int* p, int n) {
  int i = blockIdx.x * 256 + threadIdx.x;
  if (i < n) p[i] = 0;
}

__global__ void hist_kernel(const int* __restrict__ dst, int* __restrict__ deg) {
  int e = blockIdx.x * 256 + threadIdx.x;
  if (e < NE) atomicAdd(&deg[dst[e]], 1);
}

__global__ __launch_bounds__(256) void scan_a(const int* __restrict__ in,
                                              int* __restrict__ excl,
                                              int* __restrict__ bsum, int n) {
  int i = blockIdx.x * 256 + threadIdx.x;
  int v = (i < n) ? in[i] : 0;
  int lane = threadIdx.x & 63, wid = threadIdx.x >> 6;
  int incl = v;
#pragma unroll
  for (int off = 1; off < 64; off <<= 1) {
    int u = __shfl_up(incl, off);
    if (lane >= off) incl += u;
  }
  __shared__ int wsum[4];
  if (lane == 63) wsum[wid] = incl;
  __syncthreads();
  int wo = 0;
  for (int w = 0; w < wid; w++) wo += wsum[w];
  if (i < n) excl[i] = wo + incl - v;
  if (threadIdx.x == 255 && bsum) bsum[blockIdx.x] = wo + incl;
}

// finalize rowptr and init per-bucket cursors (bcur[b] = rowptr[b*128])
__global__ void scan_c(int* __restrict__ rowptr, const int* __restrict__ boff,
                       int* __restrict__ bcur, int n) {
  int i = blockIdx.x * 256 + threadIdx.x;
  if (i < n) {
    int v = rowptr[i] + boff[i >> 8];
    rowptr[i] = v;
    if ((i & 127) == 0) bcur[i >> 7] = v;
  } else if (i == n) {
    rowptr[n] = NE;
  }
}

// pass A: coarse-bucket edges (bucket = dst>>7) into bucket-major pairs.
__global__ __launch_bounds__(256) void bucket_scatter(
    const int* __restrict__ src, const int* __restrict__ dst,
    int* __restrict__ bcur, int2* __restrict__ pairs) {
  __shared__ int cnt[NBUK];
  __shared__ int base[NBUK];
  const int t = threadIdx.x;
  for (int i = t; i < NBUK; i += 256) cnt[i] = 0;
  __syncthreads();
  const int e0 = blockIdx.x * 4096;
#pragma unroll
  for (int j = 0; j < 16; ++j) {
    int e = e0 + j * 256 + t;
    if (e < NE) atomicAdd(&cnt[dst[e] >> 7], 1);
  }
  __syncthreads();
  for (int i = t; i < NBUK; i += 256) {
    int c = cnt[i];
    base[i] = c ? atomicAdd(&bcur[i], c) : 0;
    cnt[i] = 0;
  }
  __syncthreads();
#pragma unroll
  for (int j = 0; j < 16; ++j) {
    int e = e0 + j * 256 + t;
    if (e < NE) {
      int d = dst[e];
      int b = d >> 7;
      int r = atomicAdd(&cnt[b], 1);
      pairs[base[b] + r] = make_int2(src[e], d);
    }
  }
}

// pass B: per-bucket fine sort with LDS cursors.
__global__ __launch_bounds__(256) void bucket_sort(
    const int2* __restrict__ pairs, const int* __restrict__ rowptr,
    int* __restrict__ ssort) {
  __shared__ int cur[BNODES];
  const int b = blockIdx.x;
  const int n0 = b * BNODES;
  const int t = threadIdx.x;
  const int n1 = min(n0 + BNODES, NN);
  if (t < BNODES && n0 + t < NN) cur[t] = rowptr[n0 + t];
  __syncthreads();
  const int e0 = rowptr[n0];
  const int e1 = rowptr[n1];
  for (int e = e0 + t; e < e1; e += 256) {
    int2 p = pairs[e];
    int pos = atomicAdd(&cur[p.y - n0], 1);
    ssort[pos] = p.x;
  }
}

// ------- fused: logits + segment-softmax + aggregate + bias + ELU ---------
template <int MODE>
__global__ __launch_bounds__(256) void gat_aggregate(
    const ushort* __restrict__ Xl, const ushort* __restrict__ Xr,
    const float* __restrict__ att, const int* __restrict__ ssort,
    const int* __restrict__ rowptr, const float* __restrict__ bias,
    ushort* __restrict__ outb,
    const float* __restrict__ Wl3, const float* __restrict__ Wr3,
    const float* __restrict__ bl3, const float* __restrict__ br3,
    float* __restrict__ xl3, float* __restrict__ xr3) {
  int slot = threadIdx.x >> 5;
  int l = threadIdx.x & 31;
  int n = blockIdx.x * 8 + slot;
  if (n >= NN) return;
  int s0 = rowptr[n], s1 = rowptr[n + 1];
  ushort4 xru = *(const ushort4*)&Xr[n * 128 + l * 4];
  float4 xr = make_float4(bf2f(xru.x), bf2f(xru.y), bf2f(xru.z), bf2f(xru.w));
  float4 at = *(const float4*)&att[l * 4];

  float den0 = 0.f, den1 = 0.f;
  float4 A0 = make_float4(0.f, 0.f, 0.f, 0.f);
  float4 A1 = make_float4(0.f, 0.f, 0.f, 0.f);

  int i = s0;
  for (; i + 4 <= s1; i += 4) {
    int sa = ssort[i], sb = ssort[i + 1], sc = ssort[i + 2], sd = ssort[i + 3];
    ushort4 ua = *(const ushort4*)&Xl[sa * 128 + l * 4];
    ushort4 ub = *(const ushort4*)&Xl[sb * 128 + l * 4];
    ushort4 uc = *(const ushort4*)&Xl[sc * 128 + l * 4];
    ushort4 ud = *(const ushort4*)&Xl[sd * 128 + l * 4];
    float4 xa = make_float4(bf2f(ua.x), bf2f(ua.y), bf2f(ua.z), bf2f(ua.w));
    float4 xb = make_float4(bf2f(ub.x), bf2f(ub.y), bf2f(ub.z), bf2f(ub.w));
    float4 xc = make_float4(bf2f(uc.x), bf2f(uc.y), bf2f(uc.z), bf2f(uc.w));
    float4 xd = make_float4(bf2f(ud.x), bf2f(ud.y), bf2f(ud.z), bf2f(ud.w));
    float pa = at.x * lrelu(xa.x + xr.x) + at.y * lrelu(xa.y + xr.y) +
               at.z * lrelu(xa.z + xr.z) + at.w * lrelu(xa.w + xr.w);
    float pb = at.x * lrelu(xb.x + xr.x) + at.y * lrelu(xb.y + xr.y) +
               at.z * lrelu(xb.z + xr.z) + at.w * lrelu(xb.w + xr.w);
    float pc = at.x * lrelu(xc.x + xr.x) + at.y * lrelu(xc.y + xr.y) +
               at.z * lrelu(xc.z + xr.z) + at.w * lrelu(xc.w + xr.w);
    float pd = at.x * lrelu(xd.x + xr.x) + at.y * lrelu(xd.y + xr.y) +
               at.z * lrelu(xd.z + xr.z) + at.w * lrelu(xd.w + xr.w);
#pragma unroll
    for (int off = 1; off <= 4; off <<= 1) {
      pa += __shfl_xor(pa, off);
      pb += __shfl_xor(pb, off);
      pc += __shfl_xor(pc, off);
      pd += __shfl_xor(pd, off);
    }
    float wa = __expf(fminf(pa, 30.f));
    float wb = __expf(fminf(pb, 30.f));
    float wc = __expf(fminf(pc, 30.f));
    float wd = __expf(fminf(pd, 30.f));
    den0 += wa + wc;
    den1 += wb + wd;
    A0.x += wa * xa.x + wc * xc.x;  A1.x += wb * xb.x + wd * xd.x;
    A0.y += wa * xa.y + wc * xc.y;  A1.y += wb * xb.y + wd * xd.y;
    A0.z += wa * xa.z + wc * xc.z;  A1.z += wb * xb.z + wd * xd.z;
    A0.w += wa * xa.w + wc * xc.w;  A1.w += wb * xb.w + wd * xd.w;
  }
  for (; i < s1; ++i) {
    int sa = ssort[i];
    ushort4 ua = *(const ushort4*)&Xl[sa * 128 + l * 4];
    float4 xa = make_float4(bf2f(ua.x), bf2f(ua.y), bf2f(ua.z), bf2f(ua.w));
    float pa = at.x * lrelu(xa.x + xr.x) + at.y * lrelu(xa.y + xr.y) +
               at.z * lrelu(xa.z + xr.z) + at.w * lrelu(xa.w + xr.w);
#pragma unroll
    for (int off = 1; off <= 4; off <<= 1) pa += __shfl_xor(pa, off);
    float wa = __expf(fminf(pa, 30.f));
    den0 += wa;
    A0.x += wa * xa.x; A0.y += wa * xa.y; A0.z += wa * xa.z; A0.w += wa * xa.w;
  }
  float den = den0 + den1;
  float inv = 1.f / (den + 1e-16f);
  float4 b4 = *(const float4*)&bias[l * 4];
  float4 o;
  o.x = (A0.x + A1.x) * inv + b4.x;
  o.y = (A0.y + A1.y) * inv + b4.y;
  o.z = (A0.z + A1.z) * inv + b4.z;
  o.w = (A0.w + A1.w) * inv + b4.w;
  o.x = o.x > 0.f ? o.x : __expf(o.x) - 1.f;
  o.y = o.y > 0.f ? o.y : __expf(o.y) - 1.f;
  o.z = o.z > 0.f ? o.z : __expf(o.z) - 1.f;
  o.w = o.w > 0.f ? o.w : __expf(o.w) - 1.f;
  if (MODE == 0) {
    ushort4 ub;
    ub.x = f2bf(o.x); ub.y = f2bf(o.y); ub.z = f2bf(o.z); ub.w = f2bf(o.w);
    *(ushort4*)&outb[n * 128 + l * 4] = ub;
  } else {
    float4 wl = *(const float4*)&Wl3[l * 4];
    float4 wr = *(const float4*)&Wr3[l * 4];
    float sl = o.x * wl.x + o.y * wl.y + o.z * wl.z + o.w * wl.w;
    float sr = o.x * wr.x + o.y * wr.y + o.z * wr.z + o.w * wr.w;
#pragma unroll
    for (int off = 1; off <= 16; off <<= 1) {
      sl += __shfl_xor(sl, off);
      sr += __shfl_xor(sr, off);
    }
    if (l == 0) {
      xl3[n] = sl + bl3[0];
      xr3[n] = sr + br3[0];
    }
  }
}

// fused layer-3 edge phase: per-node wave, no-max softmax, wave merge
__global__ __launch_bounds__(256) void aggregate3_fused(
    const float* __restrict__ xl3, const float* __restrict__ xr3,
    const float* __restrict__ att, const int* __restrict__ ssort,
    const int* __restrict__ rowptr, const float* __restrict__ bias,
    float* __restrict__ out, int nn) {
  int wid = threadIdx.x >> 6, lane = threadIdx.x & 63;
  int n = blockIdx.x * 4 + wid;
  if (n >= nn) return;
  int s0 = rowptr[n], s1 = rowptr[n + 1];
  float xr = xr3[n];
  float a0 = att[0];
  float den = 0.f, acc = 0.f;
  for (int i = s0 + lane; i < s1; i += 64) {
    float xl = xl3[ssort[i]];
    float v = xl + xr;
    float p = a0 * (v > 0.f ? v : 0.2f * v);
    float w = __expf(fminf(p, 30.f));
    den += w;
    acc += w * xl;
  }
#pragma unroll
  for (int off = 32; off; off >>= 1) {
    den += __shfl_xor(den, off);
    acc += __shfl_xor(acc, off);
  }
  if (lane == 0) {
    float o = acc / (den + 1e-16f) + bias[0];
    out[n] = 1.f / (1.f + __expf(-o));
  }
}

extern "C" void kernel_launch(void* const* d_in, const int* in_sizes, int n_in,
                              void* d_out, int out_size, void* d_ws, size_t ws_size,
                              hipStream_t stream) {
  const float* x = (const float*)d_in[0];
  const int* ei = (const int*)d_in[1];
  const int* src = ei;
  const int* dst = ei + NE;
  const float* W_l1 = (const float*)d_in[2];
  const float* b_l1 = (const float*)d_in[3];
  const float* W_r1 = (const float*)d_in[4];
  const float* b_r1 = (const float*)d_in[5];
  const float* att1 = (const float*)d_in[6];
  const float* bias1 = (const float*)d_in[7];
  const float* W_l2 = (const float*)d_in[8];
  const float* b_l2 = (const float*)d_in[9];
  const float* W_r2 = (const float*)d_in[10];
  const float* b_r2 = (const float*)d_in[11];
  const float* att2 = (const float*)d_in[12];
  const float* bias2 = (const float*)d_in[13];
  const float* W_l3 = (const float*)d_in[14];
  const float* b_l3 = (const float*)d_in[15];
  const float* W_r3 = (const float*)d_in[16];
  const float* b_r3 = (const float*)d_in[17];
  const float* att3 = (const float*)d_in[18];
  const float* bias3 = (const float*)d_in[19];
  float* out = (float*)d_out;

  ushort* xbb = (ushort*)d_ws;           // NN*128 bf16 (gemm A input)
  ushort* xl_b = xbb + NN * 128;         // NN*128 bf16
  ushort* xr_b = xl_b + NN * 128;        // NN*128 bf16
  ushort* bpack = xr_b + NN * 128;       // 32768 bf16 packed weights
  int* deg = (int*)(bpack + 32768);      // NN
  int* rowptr = deg + NN;                // NN+1
  int* bcur = rowptr + NN + 1;           // NBUK
  int* bsum = bcur + NBUK;               // 256
  int* boff = bsum + 256;                // 256
  int* ssort = boff + 256;               // NE
  int2* pairs = (int2*)(ssort + NE);     // NE int2
  float* xl3 = (float*)(pairs + NE);     // NN
  float* xr3 = xl3 + NN;                 // NN

  const int NB_N = (NN + 255) / 256;     // 196
  const int NB_E = (NE + 255) / 256;     // 3125
  const int NB_G = (NN + 63) / 64;       // 782
  const int NB_A = (NN + 7) / 8;         // 6250
  const int NB_W4 = (NN + 3) / 4;        // 12500
  const int NB_C = (NN * 128 / 8 + 255) / 256;  // 3125
  const int NB_BK = (NE + 4095) / 4096;  // 196

  // ---- CSR build (bucketed counting sort) ----
  zero_i32<<<NB_N, 256, 0, stream>>>(deg, NN);
  hist_kernel<<<NB_E, 256, 0, stream>>>(dst, deg);
  scan_a<<<NB_N, 256, 0, stream>>>(deg, rowptr, bsum, NN);
  scan_a<<<1, 256, 0, stream>>>(bsum, boff, (int*)nullptr, NB_N);
  scan_c<<<NB_N + 1, 256, 0, stream>>>(rowptr, boff, bcur, NN);
  bucket_scatter<<<NB_BK, 256, 0, stream>>>(src, dst, bcur, pairs);
  bucket_sort<<<NBUK, 256, 0, stream>>>(pairs, rowptr, ssort);

  // ---- layer 1 ----
  cvt_bf16<<<NB_C, 256, 0, stream>>>(x, xbb, NN * 128 / 8);
  pack_w<<<16, 256, 0, stream>>>(W_l1, W_r1, bpack);
  gemm_mfma<<<NB_G, 256, 0, stream>>>(xbb, bpack, b_l1, b_r1, xl_b, xr_b, NN);
  gat_aggregate<0><<<NB_A, 256, 0, stream>>>(xl_b, xr_b, att1, ssort, rowptr, bias1,
                                             xbb, nullptr, nullptr, nullptr, nullptr,
                                             nullptr, nullptr);

  // ---- layer 2 (+ fused layer-3 GEMV epilogue) ----
  pack_w<<<16, 256, 0, stream>>>(W_l2, W_r2, bpack);
  gemm_mfma<<<NB_G, 256, 0, stream>>>(xbb, bpack, b_l2, b_r2, xl_b, xr_b, NN);
  gat_aggregate<1><<<NB_A, 256, 0, stream>>>(xl_b, xr_b, att2, ssort, rowptr, bias2,
                                             nullptr, W_l3, W_r3, b_l3, b_r3,
                                             xl3, xr3);

  // ---- layer 3 edge phase ----
  aggregate3_fused<<<NB_W4, 256, 0, stream>>>(xl3, xr3, att3, ssort, rowptr, bias3, out, NN);
}

// Round 12
// 335.547 us; speedup vs baseline: 1.4478x; 1.0250x over previous
//
#include <hip/hip_runtime.h>
#include <hip/hip_bf16.h>
#include <math.h>

#define NN 50000
#define NE 800000
#define NBUK 391      // ceil(NN/128)
#define BNODES 128

typedef __attribute__((ext_vector_type(8))) short bf16x8;
typedef __attribute__((ext_vector_type(4))) float f32x4;

__device__ __forceinline__ float lrelu(float x) { return x > 0.f ? x : 0.2f * x; }

__device__ __forceinline__ ushort f2bf(float v) {
  __hip_bfloat16 h = __float2bfloat16(v);
  return *(ushort*)&h;
}
__device__ __forceinline__ float bf2f(ushort u) {
  return __uint_as_float(((unsigned int)u) << 16);
}

// -------- convert fp32 activations -> bf16 (8 elems/thread) ---------------
__global__ void cvt_bf16(const float* __restrict__ in, ushort* __restrict__ out, int n8) {
  int i = blockIdx.x * 256 + threadIdx.x;
  if (i >= n8) return;
  float4 v0 = *(const float4*)&in[i * 8];
  float4 v1 = *(const float4*)&in[i * 8 + 4];
  ushort4 a, b;
  a.x = f2bf(v0.x); a.y = f2bf(v0.y); a.z = f2bf(v0.z); a.w = f2bf(v0.w);
  b.x = f2bf(v1.x); b.y = f2bf(v1.y); b.z = f2bf(v1.z); b.w = f2bf(v1.w);
  *(ushort4*)&out[i * 8] = a;
  *(ushort4*)&out[i * 8 + 4] = b;
}

// -------- pack Wl|Wr (fp32 [128][128] each) into MFMA B-frag bf16 layout ---
__global__ void pack_w(const float* __restrict__ Wl, const float* __restrict__ Wr,
                       ushort* __restrict__ Bpack) {
  int t = blockIdx.x * 256 + threadIdx.x;   // (kt,col,hi): 4*256*4 = 4096
  if (t >= 4096) return;
  int hi = t & 3;
  int col = (t >> 2) & 255;
  int kt = t >> 10;
  const float* W = (col < 128) ? (Wl + col) : (Wr + (col - 128));
  ushort4 u0, u1;
  int k0 = kt * 32 + hi * 8;
  u0.x = f2bf(W[(k0 + 0) * 128]); u0.y = f2bf(W[(k0 + 1) * 128]);
  u0.z = f2bf(W[(k0 + 2) * 128]); u0.w = f2bf(W[(k0 + 3) * 128]);
  u1.x = f2bf(W[(k0 + 4) * 128]); u1.y = f2bf(W[(k0 + 5) * 128]);
  u1.z = f2bf(W[(k0 + 6) * 128]); u1.w = f2bf(W[(k0 + 7) * 128]);
  *(ushort4*)&Bpack[t * 8] = u0;
  *(ushort4*)&Bpack[t * 8 + 4] = u1;
}

// -------- MFMA dual GEMM: [Xl|Xr](bf16) = Abf @ [Wl|Wr] + [bl|br] ---------
__global__ __launch_bounds__(256) void gemm_mfma(
    const ushort* __restrict__ Abf, const ushort* __restrict__ Bpack,
    const float* __restrict__ bl, const float* __restrict__ br,
    ushort* __restrict__ Xl, ushort* __restrict__ Xr, int n) {
  const int tid = threadIdx.x;
  const int wv = tid >> 6;
  const int l = tid & 63;
  const int lr = l & 15;
  const int hi = l >> 4;
  const int r0 = blockIdx.x * 64;

  f32x4 acc[4][4];
#pragma unroll
  for (int mi = 0; mi < 4; ++mi)
#pragma unroll
    for (int nj = 0; nj < 4; ++nj) acc[mi][nj] = (f32x4)0.f;

#pragma unroll
  for (int kt = 0; kt < 4; ++kt) {
    bf16x8 b[4], a[4];
#pragma unroll
    for (int nj = 0; nj < 4; ++nj) {
      int col = wv * 64 + nj * 16 + lr;
      b[nj] = *(const bf16x8*)&Bpack[((kt * 256 + col) * 4 + hi) * 8];
    }
#pragma unroll
    for (int mi = 0; mi < 4; ++mi) {
      int row = r0 + mi * 16 + lr;
      row = row < n ? row : n - 1;     // clamp tail reads (stores guarded)
      a[mi] = *(const bf16x8*)&Abf[row * 128 + kt * 32 + hi * 8];
    }
#pragma unroll
    for (int mi = 0; mi < 4; ++mi)
#pragma unroll
      for (int nj = 0; nj < 4; ++nj)
        acc[mi][nj] = __builtin_amdgcn_mfma_f32_16x16x32_bf16(a[mi], b[nj], acc[mi][nj], 0, 0, 0);
  }

#pragma unroll
  for (int nj = 0; nj < 4; ++nj) {
    int col = wv * 64 + nj * 16 + lr;
    float bb = (col < 128) ? bl[col] : br[col - 128];
    ushort* dst = (col < 128) ? (Xl + col) : (Xr + (col - 128));
#pragma unroll
    for (int mi = 0; mi < 4; ++mi) {
#pragma unroll
      for (int v = 0; v < 4; ++v) {
        int row = r0 + mi * 16 + hi * 4 + v;
        if (row < n) dst[row * 128] = f2bf(acc[mi][nj][v] + bb);
      }
    }
  }
}

// ---------------- CSR build ----------------
__global__ void zero_i32(int* p, int n) {
  int i = blockIdx.x * 256 + threadIdx.x;
  if (i < n) p[i] = 0;
}

__global__ void hist_kernel(const int* __restrict__ dst, int* __restrict__ deg) {
  int e = blockIdx.x * 256 + threadIdx.x;
  if (e < NE) atomicAdd(&deg[dst[e]], 1);
}

__global__ __launch_bounds__(256) void scan_a(const int* __restrict__ in,
                                              int* __restrict__ excl,
                                              int* __restrict__ bsum, int n) {
  int i = blockIdx.x * 256 + threadIdx.x;
  int v = (i < n) ? in[i] : 0;
  int lane = threadIdx.x & 63, wid = threadIdx.x >> 6;
  int incl = v;
#pragma unroll
  for (int off = 1; off < 64; off <<= 1) {
    int u = __shfl_up(incl, off);
    if (lane >= off) incl += u;
  }
  __shared__ int wsum[4];
  if (lane == 63) wsum[wid] = incl;
  __syncthreads();
  int wo = 0;
  for (int w = 0; w < wid; w++) wo += wsum[w];
  if (i < n) excl[i] = wo + incl - v;
  if (threadIdx.x == 255 && bsum) bsum[blockIdx.x] = wo + incl;
}

// finalize rowptr and init per-bucket cursors (bcur[b] = rowptr[b*128])
__global__ void scan_c(int* __restrict__ rowptr, const int* __restrict__ boff,
                       int* __restrict__ bcur, int n) {
  int i = blockIdx.x * 256 + threadIdx.x;
  if (i < n) {
    int v = rowptr[i] + boff[i >> 8];
    rowptr[i] = v;
    if ((i & 127) == 0) bcur[i >> 7] = v;
  } else if (i == n) {
    rowptr[n] = NE;
  }
}

// pass A: coarse-bucket edges (bucket = dst>>7) into bucket-major pairs.
__global__ __launch_bounds__(256) void bucket_scatter(
    const int* __restrict__ src, const int* __restrict__ dst,
    int* __restrict__ bcur, int2* __restrict__ pairs) {
  __shared__ int cnt[NBUK];
  __shared__ int base[NBUK];
  const int t = threadIdx.x;
  for (int i = t; i < NBUK; i += 256) cnt[i] = 0;
  __syncthreads();
  const int e0 = blockIdx.x * 4096;
#pragma unroll
  for (int j = 0; j < 16; ++j) {
    int e = e0 + j * 256 + t;
    if (e < NE) atomicAdd(&cnt[dst[e] >> 7], 1);
  }
  __syncthreads();
  for (int i = t; i < NBUK; i += 256) {
    int c = cnt[i];
    base[i] = c ? atomicAdd(&bcur[i], c) : 0;
    cnt[i] = 0;
  }
  __syncthreads();
#pragma unroll
  for (int j = 0; j < 16; ++j) {
    int e = e0 + j * 256 + t;
    if (e < NE) {
      int d = dst[e];
      int b = d >> 7;
      int r = atomicAdd(&cnt[b], 1);
      pairs[base[b] + r] = make_int2(src[e], d);
    }
  }
}

// pass B: per-bucket fine sort with LDS cursors.
__global__ __launch_bounds__(256) void bucket_sort(
    const int2* __restrict__ pairs, const int* __restrict__ rowptr,
    int* __restrict__ ssort) {
  __shared__ int cur[BNODES];
  const int b = blockIdx.x;
  const int n0 = b * BNODES;
  const int t = threadIdx.x;
  const int n1 = min(n0 + BNODES, NN);
  if (t < BNODES && n0 + t < NN) cur[t] = rowptr[n0 + t];
  __syncthreads();
  const int e0 = rowptr[n0];
  const int e1 = rowptr[n1];
  for (int e = e0 + t; e < e1; e += 256) {
    int2 p = pairs[e];
    int pos = atomicAdd(&cur[p.y - n0], 1);
    ssort[pos] = p.x;
  }
}

// ------- fused: logits + segment-softmax + aggregate + bias + ELU ---------
// VALU-lean logit: att*lrelu(v) = (0.6att)*v + (0.4att)*|v|; |v| is a free
// VALU input modifier. log2e folded into the att scales -> raw exp2f.
template <int MODE>
__global__ __launch_bounds__(256) void gat_aggregate(
    const ushort* __restrict__ Xl, const ushort* __restrict__ Xr,
    const float* __restrict__ att, const int* __restrict__ ssort,
    const int* __restrict__ rowptr, const float* __restrict__ bias,
    ushort* __restrict__ outb,
    const float* __restrict__ Wl3, const float* __restrict__ Wr3,
    const float* __restrict__ bl3, const float* __restrict__ br3,
    float* __restrict__ xl3, float* __restrict__ xr3) {
  int slot = threadIdx.x >> 5;
  int l = threadIdx.x & 31;
  int n = blockIdx.x * 8 + slot;
  if (n >= NN) return;
  int s0 = rowptr[n], s1 = rowptr[n + 1];
  ushort4 xru = *(const ushort4*)&Xr[n * 128 + l * 4];
  float4 xr = make_float4(bf2f(xru.x), bf2f(xru.y), bf2f(xru.z), bf2f(xru.w));
  float4 at = *(const float4*)&att[l * 4];
  const float L2E = 1.44269504f;
  float4 a6, a4;
  a6.x = 0.6f * L2E * at.x; a6.y = 0.6f * L2E * at.y;
  a6.z = 0.6f * L2E * at.z; a6.w = 0.6f * L2E * at.w;
  a4.x = 0.4f * L2E * at.x; a4.y = 0.4f * L2E * at.y;
  a4.z = 0.4f * L2E * at.z; a4.w = 0.4f * L2E * at.w;

  float den0 = 0.f, den1 = 0.f;
  float4 A0 = make_float4(0.f, 0.f, 0.f, 0.f);
  float4 A1 = make_float4(0.f, 0.f, 0.f, 0.f);

  int i = s0;
  for (; i + 4 <= s1; i += 4) {
    int sa = ssort[i], sb = ssort[i + 1], sc = ssort[i + 2], sd = ssort[i + 3];
    ushort4 ua = *(const ushort4*)&Xl[sa * 128 + l * 4];
    ushort4 ub = *(const ushort4*)&Xl[sb * 128 + l * 4];
    ushort4 uc = *(const ushort4*)&Xl[sc * 128 + l * 4];
    ushort4 ud = *(const ushort4*)&Xl[sd * 128 + l * 4];
    float4 xa = make_float4(bf2f(ua.x), bf2f(ua.y), bf2f(ua.z), bf2f(ua.w));
    float4 xb = make_float4(bf2f(ub.x), bf2f(ub.y), bf2f(ub.z), bf2f(ub.w));
    float4 xc = make_float4(bf2f(uc.x), bf2f(uc.y), bf2f(uc.z), bf2f(uc.w));
    float4 xd = make_float4(bf2f(ud.x), bf2f(ud.y), bf2f(ud.z), bf2f(ud.w));
    float va, pa = 0.f, pb = 0.f, pc = 0.f, pd = 0.f;
    va = xa.x + xr.x; pa = fmaf(a6.x, va, pa); pa = fmaf(a4.x, fabsf(va), pa);
    va = xa.y + xr.y; pa = fmaf(a6.y, va, pa); pa = fmaf(a4.y, fabsf(va), pa);
    va = xa.z + xr.z; pa = fmaf(a6.z, va, pa); pa = fmaf(a4.z, fabsf(va), pa);
    va = xa.w + xr.w; pa = fmaf(a6.w, va, pa); pa = fmaf(a4.w, fabsf(va), pa);
    va = xb.x + xr.x; pb = fmaf(a6.x, va, pb); pb = fmaf(a4.x, fabsf(va), pb);
    va = xb.y + xr.y; pb = fmaf(a6.y, va, pb); pb = fmaf(a4.y, fabsf(va), pb);
    va = xb.z + xr.z; pb = fmaf(a6.z, va, pb); pb = fmaf(a4.z, fabsf(va), pb);
    va = xb.w + xr.w; pb = fmaf(a6.w, va, pb); pb = fmaf(a4.w, fabsf(va), pb);
    va = xc.x + xr.x; pc = fmaf(a6.x, va, pc); pc = fmaf(a4.x, fabsf(va), pc);
    va = xc.y + xr.y; pc = fmaf(a6.y, va, pc); pc = fmaf(a4.y, fabsf(va), pc);
    va = xc.z + xr.z; pc = fmaf(a6.z, va, pc); pc = fmaf(a4.z, fabsf(va), pc);
    va = xc.w + xr.w; pc = fmaf(a6.w, va, pc); pc = fmaf(a4.w, fabsf(va), pc);
    va = xd.x + xr.x; pd = fmaf(a6.x, va, pd); pd = fmaf(a4.x, fabsf(va), pd);
    va = xd.y + xr.y; pd = fmaf(a6.y, va, pd); pd = fmaf(a4.y, fabsf(va), pd);
    va = xd.z + xr.z; pd = fmaf(a6.z, va, pd); pd = fmaf(a4.z, fabsf(va), pd);
    va = xd.w + xr.w; pd = fmaf(a6.w, va, pd); pd = fmaf(a4.w, fabsf(va), pd);
#pragma unroll
    for (int off = 1; off <= 4; off <<= 1) {
      pa += __shfl_xor(pa, off);
      pb += __shfl_xor(pb, off);
      pc += __shfl_xor(pc, off);
      pd += __shfl_xor(pd, off);
    }
    float wa = exp2f(fminf(pa, 43.f));
    float wb = exp2f(fminf(pb, 43.f));
    float wc = exp2f(fminf(pc, 43.f));
    float wd = exp2f(fminf(pd, 43.f));
    den0 += wa + wc;
    den1 += wb + wd;
    A0.x += wa * xa.x + wc * xc.x;  A1.x += wb * xb.x + wd * xd.x;
    A0.y += wa * xa.y + wc * xc.y;  A1.y += wb * xb.y + wd * xd.y;
    A0.z += wa * xa.z + wc * xc.z;  A1.z += wb * xb.z + wd * xd.z;
    A0.w += wa * xa.w + wc * xc.w;  A1.w += wb * xb.w + wd * xd.w;
  }
  for (; i < s1; ++i) {
    int sa = ssort[i];
    ushort4 ua = *(const ushort4*)&Xl[sa * 128 + l * 4];
    float4 xa = make_float4(bf2f(ua.x), bf2f(ua.y), bf2f(ua.z), bf2f(ua.w));
    float va, pa = 0.f;
    va = xa.x + xr.x; pa = fmaf(a6.x, va, pa); pa = fmaf(a4.x, fabsf(va), pa);
    va = xa.y + xr.y; pa = fmaf(a6.y, va, pa); pa = fmaf(a4.y, fabsf(va), pa);
    va = xa.z + xr.z; pa = fmaf(a6.z, va, pa); pa = fmaf(a4.z, fabsf(va), pa);
    va = xa.w + xr.w; pa = fmaf(a6.w, va, pa); pa = fmaf(a4.w, fabsf(va), pa);
#pragma unroll
    for (int off = 1; off <= 4; off <<= 1) pa += __shfl_xor(pa, off);
    float wa = exp2f(fminf(pa, 43.f));
    den0 += wa;
    A0.x += wa * xa.x; A0.y += wa * xa.y; A0.z += wa * xa.z; A0.w += wa * xa.w;
  }
  float den = den0 + den1;
  float inv = 1.f / (den + 1e-16f);
  float4 b4 = *(const float4*)&bias[l * 4];
  float4 o;
  o.x = (A0.x + A1.x) * inv + b4.x;
  o.y = (A0.y + A1.y) * inv + b4.y;
  o.z = (A0.z + A1.z) * inv + b4.z;
  o.w = (A0.w + A1.w) * inv + b4.w;
  o.x = o.x > 0.f ? o.x : __expf(o.x) - 1.f;
  o.y = o.y > 0.f ? o.y : __expf(o.y) - 1.f;
  o.z = o.z > 0.f ? o.z : __expf(o.z) - 1.f;
  o.w = o.w > 0.f ? o.w : __expf(o.w) - 1.f;
  if (MODE == 0) {
    ushort4 ub;
    ub.x = f2bf(o.x); ub.y = f2bf(o.y); ub.z = f2bf(o.z); ub.w = f2bf(o.w);
    *(ushort4*)&outb[n * 128 + l * 4] = ub;
  } else {
    float4 wl = *(const float4*)&Wl3[l * 4];
    float4 wr = *(const float4*)&Wr3[l * 4];
    float sl = o.x * wl.x + o.y * wl.y + o.z * wl.z + o.w * wl.w;
    float sr = o.x * wr.x + o.y * wr.y + o.z * wr.z + o.w * wr.w;
#pragma unroll
    for (int off = 1; off <= 16; off <<= 1) {
      sl += __shfl_xor(sl, off);
      sr += __shfl_xor(sr, off);
    }
    if (l == 0) {
      xl3[n] = sl + bl3[0];
      xr3[n] = sr + br3[0];
    }
  }
}

// fused layer-3 edge phase: per-node wave, no-max softmax, wave merge
__global__ __launch_bounds__(256) void aggregate3_fused(
    const float* __restrict__ xl3, const float* __restrict__ xr3,
    const float* __restrict__ att, const int* __restrict__ ssort,
    const int* __restrict__ rowptr, const float* __restrict__ bias,
    float* __restrict__ out, int nn) {
  int wid = threadIdx.x >> 6, lane = threadIdx.x & 63;
  int n = blockIdx.x * 4 + wid;
  if (n >= nn) return;
  int s0 = rowptr[n], s1 = rowptr[n + 1];
  float xr = xr3[n];
  const float L2E = 1.44269504f;
  float s6 = 0.6f * L2E * att[0];
  float s4 = 0.4f * L2E * att[0];
  float den = 0.f, acc = 0.f;
  for (int i = s0 + lane; i < s1; i += 64) {
    float xl = xl3[ssort[i]];
    float v = xl + xr;
    float p = fmaf(s6, v, s4 * fabsf(v));
    float w = exp2f(fminf(p, 43.f));
    den += w;
    acc += w * xl;
  }
#pragma unroll
  for (int off = 32; off; off >>= 1) {
    den += __shfl_xor(den, off);
    acc += __shfl_xor(acc, off);
  }
  if (lane == 0) {
    float o = acc / (den + 1e-16f) + bias[0];
    out[n] = 1.f / (1.f + __expf(-o));
  }
}

extern "C" void kernel_launch(void* const* d_in, const int* in_sizes, int n_in,
                              void* d_out, int out_size, void* d_ws, size_t ws_size,
                              hipStream_t stream) {
  const float* x = (const float*)d_in[0];
  const int* ei = (const int*)d_in[1];
  const int* src = ei;
  const int* dst = ei + NE;
  const float* W_l1 = (const float*)d_in[2];
  const float* b_l1 = (const float*)d_in[3];
  const float* W_r1 = (const float*)d_in[4];
  const float* b_r1 = (const float*)d_in[5];
  const float* att1 = (const float*)d_in[6];
  const float* bias1 = (const float*)d_in[7];
  const float* W_l2 = (const float*)d_in[8];
  const float* b_l2 = (const float*)d_in[9];
  const float* W_r2 = (const float*)d_in[10];
  const float* b_r2 = (const float*)d_in[11];
  const float* att2 = (const float*)d_in[12];
  const float* bias2 = (const float*)d_in[13];
  const float* W_l3 = (const float*)d_in[14];
  const float* b_l3 = (const float*)d_in[15];
  const float* W_r3 = (const float*)d_in[16];
  const float* b_r3 = (const float*)d_in[17];
  const float* att3 = (const float*)d_in[18];
  const float* bias3 = (const float*)d_in[19];
  float* out = (float*)d_out;

  ushort* xbb = (ushort*)d_ws;           // NN*128 bf16 (gemm A input)
  ushort* xl_b = xbb + NN * 128;         // NN*128 bf16
  ushort* xr_b = xl_b + NN * 128;        // NN*128 bf16
  ushort* bpack = xr_b + NN * 128;       // 32768 bf16 packed weights
  int* deg = (int*)(bpack + 32768);      // NN
  int* rowptr = deg + NN;                // NN+1
  int* bcur = rowptr + NN + 1;           // NBUK
  int* bsum = bcur + NBUK;               // 256
  int* boff = bsum + 256;                // 256
  int* ssort = boff + 256;               // NE
  int2* pairs = (int2*)(ssort + NE);     // NE int2
  float* xl3 = (float*)(pairs + NE);     // NN
  float* xr3 = xl3 + NN;                 // NN

  const int NB_N = (NN + 255) / 256;     // 196
  const int NB_E = (NE + 255) / 256;     // 3125
  const int NB_G = (NN + 63) / 64;       // 782
  const int NB_A = (NN + 7) / 8;         // 6250
  const int NB_W4 = (NN + 3) / 4;        // 12500
  const int NB_C = (NN * 128 / 8 + 255) / 256;  // 3125
  const int NB_BK = (NE + 4095) / 4096;  // 196

  // ---- CSR build (bucketed counting sort) ----
  zero_i32<<<NB_N, 256, 0, stream>>>(deg, NN);
  hist_kernel<<<NB_E, 256, 0, stream>>>(dst, deg);
  scan_a<<<NB_N, 256, 0, stream>>>(deg, rowptr, bsum, NN);
  scan_a<<<1, 256, 0, stream>>>(bsum, boff, (int*)nullptr, NB_N);
  scan_c<<<NB_N + 1, 256, 0, stream>>>(rowptr, boff, bcur, NN);
  bucket_scatter<<<NB_BK, 256, 0, stream>>>(src, dst, bcur, pairs);
  bucket_sort<<<NBUK, 256, 0, stream>>>(pairs, rowptr, ssort);

  // ---- layer 1 ----
  cvt_bf16<<<NB_C, 256, 0, stream>>>(x, xbb, NN * 128 / 8);
  pack_w<<<16, 256, 0, stream>>>(W_l1, W_r1, bpack);
  gemm_mfma<<<NB_G, 256, 0, stream>>>(xbb, bpack, b_l1, b_r1, xl_b, xr_b, NN);
  gat_aggregate<0><<<NB_A, 256, 0, stream>>>(xl_b, xr_b, att1, ssort, rowptr, bias1,
                                             xbb, nullptr, nullptr, nullptr, nullptr,
                                             nullptr, nullptr);

  // ---- layer 2 (+ fused layer-3 GEMV epilogue) ----
  pack_w<<<16, 256, 0, stream>>>(W_l2, W_r2, bpack);
  gemm_mfma<<<NB_G, 256, 0, stream>>>(xbb, bpack, b_l2, b_r2, xl_b, xr_b, NN);
  gat_aggregate<1><<<NB_A, 256, 0, stream>>>(xl_b, xr_b, att2, ssort, rowptr, bias2,
                                             nullptr, W_l3, W_r3, b_l3, b_r3,
                                             xl3, xr3);

  // ---- layer 3 edge phase ----
  aggregate3_fused<<<NB_W4, 256, 0, stream>>>(xl3, xr3, att3, ssort, rowptr, bias3, out, NN);
}

// Round 13
// 312.041 us; speedup vs baseline: 1.5569x; 1.0753x over previous
//
#include <hip/hip_runtime.h>
#include <hip/hip_bf16.h>
#include <math.h>

#define NN 50000
#define NE 800000
#define NBUK 391      // ceil(NN/128)
#define BNODES 128

typedef __attribute__((ext_vector_type(8))) short bf16x8;
typedef __attribute__((ext_vector_type(4))) float f32x4;
typedef __attribute__((ext_vector_type(8))) unsigned short ushort8v;

__device__ __forceinline__ float lrelu(float x) { return x > 0.f ? x : 0.2f * x; }

__device__ __forceinline__ ushort f2bf(float v) {
  __hip_bfloat16 h = __float2bfloat16(v);
  return *(ushort*)&h;
}
__device__ __forceinline__ float bf2f(ushort u) {
  return __uint_as_float(((unsigned int)u) << 16);
}

// -------- convert fp32 activations -> bf16 (8 elems/thread) ---------------
__global__ void cvt_bf16(const float* __restrict__ in, ushort* __restrict__ out, int n8) {
  int i = blockIdx.x * 256 + threadIdx.x;
  if (i >= n8) return;
  float4 v0 = *(const float4*)&in[i * 8];
  float4 v1 = *(const float4*)&in[i * 8 + 4];
  ushort4 a, b;
  a.x = f2bf(v0.x); a.y = f2bf(v0.y); a.z = f2bf(v0.z); a.w = f2bf(v0.w);
  b.x = f2bf(v1.x); b.y = f2bf(v1.y); b.z = f2bf(v1.z); b.w = f2bf(v1.w);
  *(ushort4*)&out[i * 8] = a;
  *(ushort4*)&out[i * 8 + 4] = b;
}

// -------- pack Wl|Wr (fp32 [128][128] each) into MFMA B-frag bf16 layout ---
__global__ void pack_w(const float* __restrict__ Wl, const float* __restrict__ Wr,
                       ushort* __restrict__ Bpack) {
  int t = blockIdx.x * 256 + threadIdx.x;   // (kt,col,hi): 4*256*4 = 4096
  if (t >= 4096) return;
  int hi = t & 3;
  int col = (t >> 2) & 255;
  int kt = t >> 10;
  const float* W = (col < 128) ? (Wl + col) : (Wr + (col - 128));
  ushort4 u0, u1;
  int k0 = kt * 32 + hi * 8;
  u0.x = f2bf(W[(k0 + 0) * 128]); u0.y = f2bf(W[(k0 + 1) * 128]);
  u0.z = f2bf(W[(k0 + 2) * 128]); u0.w = f2bf(W[(k0 + 3) * 128]);
  u1.x = f2bf(W[(k0 + 4) * 128]); u1.y = f2bf(W[(k0 + 5) * 128]);
  u1.z = f2bf(W[(k0 + 6) * 128]); u1.w = f2bf(W[(k0 + 7) * 128]);
  *(ushort4*)&Bpack[t * 8] = u0;
  *(ushort4*)&Bpack[t * 8 + 4] = u1;
}

// -------- MFMA dual GEMM: [Xl|Xr](bf16) = Abf @ [Wl|Wr] + [bl|br] ---------
// 64 rows x 256 cols per block, 4 waves. Epilogue stages the bf16 tile in
// LDS then stores coalesced ushort8 chunks (the old per-column scalar 2B
// stores at stride 256B caused ~2x write amplification and ~40us/gemm).
__global__ __launch_bounds__(256) void gemm_mfma(
    const ushort* __restrict__ Abf, const ushort* __restrict__ Bpack,
    const float* __restrict__ bl, const float* __restrict__ br,
    ushort* __restrict__ Xl, ushort* __restrict__ Xr, int n) {
  __shared__ ushort tile[64][264];   // row stride 528B (16B-aligned)
  const int tid = threadIdx.x;
  const int wv = tid >> 6;
  const int l = tid & 63;
  const int lr = l & 15;
  const int hi = l >> 4;
  const int r0 = blockIdx.x * 64;

  f32x4 acc[4][4];
#pragma unroll
  for (int mi = 0; mi < 4; ++mi)
#pragma unroll
    for (int nj = 0; nj < 4; ++nj) acc[mi][nj] = (f32x4)0.f;

#pragma unroll
  for (int kt = 0; kt < 4; ++kt) {
    bf16x8 b[4], a[4];
#pragma unroll
    for (int nj = 0; nj < 4; ++nj) {
      int col = wv * 64 + nj * 16 + lr;
      b[nj] = *(const bf16x8*)&Bpack[((kt * 256 + col) * 4 + hi) * 8];
    }
#pragma unroll
    for (int mi = 0; mi < 4; ++mi) {
      int row = r0 + mi * 16 + lr;
      row = row < n ? row : n - 1;     // clamp tail reads (stores guarded)
      a[mi] = *(const bf16x8*)&Abf[row * 128 + kt * 32 + hi * 8];
    }
#pragma unroll
    for (int mi = 0; mi < 4; ++mi)
#pragma unroll
      for (int nj = 0; nj < 4; ++nj)
        acc[mi][nj] = __builtin_amdgcn_mfma_f32_16x16x32_bf16(a[mi], b[nj], acc[mi][nj], 0, 0, 0);
  }

  // acc -> LDS (bias added)
#pragma unroll
  for (int nj = 0; nj < 4; ++nj) {
    int col = wv * 64 + nj * 16 + lr;
    float bb = (col < 128) ? bl[col] : br[col - 128];
#pragma unroll
    for (int mi = 0; mi < 4; ++mi)
#pragma unroll
      for (int v = 0; v < 4; ++v)
        tile[mi * 16 + hi * 4 + v][col] = f2bf(acc[mi][nj][v] + bb);
  }
  __syncthreads();

  // coalesced store: 8 chunks of 16B per thread
#pragma unroll
  for (int j = 0; j < 8; ++j) {
    int c = j * 256 + tid;          // 0..2047
    int rl = c >> 5;                // local row
    int colc = (c & 31) * 8;        // col chunk start
    int row = r0 + rl;
    if (row < n) {
      ushort* dstp = (colc < 128) ? &Xl[row * 128 + colc] : &Xr[row * 128 + (colc - 128)];
      *(ushort8v*)dstp = *(const ushort8v*)&tile[rl][colc];
    }
  }
}

// ---------------- CSR build ----------------
__global__ void zero_i32(int* p, int n) {
  int i = blockIdx.x * 256 + threadIdx.x;
  if (i < n) p[i] = 0;
}

__global__ void hist_kernel(const int* __restrict__ dst, int* __restrict__ deg) {
  int e = blockIdx.x * 256 + threadIdx.x;
  if (e < NE) atomicAdd(&deg[dst[e]], 1);
}

__global__ __launch_bounds__(256) void scan_a(const int* __restrict__ in,
                                              int* __restrict__ excl,
                                              int* __restrict__ bsum, int n) {
  int i = blockIdx.x * 256 + threadIdx.x;
  int v = (i < n) ? in[i] : 0;
  int lane = threadIdx.x & 63, wid = threadIdx.x >> 6;
  int incl = v;
#pragma unroll
  for (int off = 1; off < 64; off <<= 1) {
    int u = __shfl_up(incl, off);
    if (lane >= off) incl += u;
  }
  __shared__ int wsum[4];
  if (lane == 63) wsum[wid] = incl;
  __syncthreads();
  int wo = 0;
  for (int w = 0; w < wid; w++) wo += wsum[w];
  if (i < n) excl[i] = wo + incl - v;
  if (threadIdx.x == 255 && bsum) bsum[blockIdx.x] = wo + incl;
}

// finalize rowptr and init per-bucket cursors (bcur[b] = rowptr[b*128])
__global__ void scan_c(int* __restrict__ rowptr, const int* __restrict__ boff,
                       int* __restrict__ bcur, int n) {
  int i = blockIdx.x * 256 + threadIdx.x;
  if (i < n) {
    int v = rowptr[i] + boff[i >> 8];
    rowptr[i] = v;
    if ((i & 127) == 0) bcur[i >> 7] = v;
  } else if (i == n) {
    rowptr[n] = NE;
  }
}

// pass A: coarse-bucket edges (bucket = dst>>7) into bucket-major pairs.
__global__ __launch_bounds__(256) void bucket_scatter(
    const int* __restrict__ src, const int* __restrict__ dst,
    int* __restrict__ bcur, int2* __restrict__ pairs) {
  __shared__ int cnt[NBUK];
  __shared__ int base[NBUK];
  const int t = threadIdx.x;
  for (int i = t; i < NBUK; i += 256) cnt[i] = 0;
  __syncthreads();
  const int e0 = blockIdx.x * 4096;
#pragma unroll
  for (int j = 0; j < 16; ++j) {
    int e = e0 + j * 256 + t;
    if (e < NE) atomicAdd(&cnt[dst[e] >> 7], 1);
  }
  __syncthreads();
  for (int i = t; i < NBUK; i += 256) {
    int c = cnt[i];
    base[i] = c ? atomicAdd(&bcur[i], c) : 0;
    cnt[i] = 0;
  }
  __syncthreads();
#pragma unroll
  for (int j = 0; j < 16; ++j) {
    int e = e0 + j * 256 + t;
    if (e < NE) {
      int d = dst[e];
      int b = d >> 7;
      int r = atomicAdd(&cnt[b], 1);
      pairs[base[b] + r] = make_int2(src[e], d);
    }
  }
}

// pass B: per-bucket fine sort with LDS cursors.
__global__ __launch_bounds__(256) void bucket_sort(
    const int2* __restrict__ pairs, const int* __restrict__ rowptr,
    int* __restrict__ ssort) {
  __shared__ int cur[BNODES];
  const int b = blockIdx.x;
  const int n0 = b * BNODES;
  const int t = threadIdx.x;
  const int n1 = min(n0 + BNODES, NN);
  if (t < BNODES && n0 + t < NN) cur[t] = rowptr[n0 + t];
  __syncthreads();
  const int e0 = rowptr[n0];
  const int e1 = rowptr[n1];
  for (int e = e0 + t; e < e1; e += 256) {
    int2 p = pairs[e];
    int pos = atomicAdd(&cur[p.y - n0], 1);
    ssort[pos] = p.x;
  }
}

// ------- fused: logits + segment-softmax + aggregate + bias + ELU ---------
// VALU-lean logit: att*lrelu(v) = (0.6att)*v + (0.4att)*|v|; log2e folded.
template <int MODE>
__global__ __launch_bounds__(256) void gat_aggregate(
    const ushort* __restrict__ Xl, const ushort* __restrict__ Xr,
    const float* __restrict__ att, const int* __restrict__ ssort,
    const int* __restrict__ rowptr, const float* __restrict__ bias,
    ushort* __restrict__ outb,
    const float* __restrict__ Wl3, const float* __restrict__ Wr3,
    const float* __restrict__ bl3, const float* __restrict__ br3,
    float* __restrict__ xl3, float* __restrict__ xr3) {
  int slot = threadIdx.x >> 5;
  int l = threadIdx.x & 31;
  int n = blockIdx.x * 8 + slot;
  if (n >= NN) return;
  int s0 = rowptr[n], s1 = rowptr[n + 1];
  ushort4 xru = *(const ushort4*)&Xr[n * 128 + l * 4];
  float4 xr = make_float4(bf2f(xru.x), bf2f(xru.y), bf2f(xru.z), bf2f(xru.w));
  float4 at = *(const float4*)&att[l * 4];
  const float L2E = 1.44269504f;
  float4 a6, a4;
  a6.x = 0.6f * L2E * at.x; a6.y = 0.6f * L2E * at.y;
  a6.z = 0.6f * L2E * at.z; a6.w = 0.6f * L2E * at.w;
  a4.x = 0.4f * L2E * at.x; a4.y = 0.4f * L2E * at.y;
  a4.z = 0.4f * L2E * at.z; a4.w = 0.4f * L2E * at.w;

  float den0 = 0.f, den1 = 0.f;
  float4 A0 = make_float4(0.f, 0.f, 0.f, 0.f);
  float4 A1 = make_float4(0.f, 0.f, 0.f, 0.f);

  int i = s0;
  for (; i + 4 <= s1; i += 4) {
    int sa = ssort[i], sb = ssort[i + 1], sc = ssort[i + 2], sd = ssort[i + 3];
    ushort4 ua = *(const ushort4*)&Xl[sa * 128 + l * 4];
    ushort4 ub = *(const ushort4*)&Xl[sb * 128 + l * 4];
    ushort4 uc = *(const ushort4*)&Xl[sc * 128 + l * 4];
    ushort4 ud = *(const ushort4*)&Xl[sd * 128 + l * 4];
    float4 xa = make_float4(bf2f(ua.x), bf2f(ua.y), bf2f(ua.z), bf2f(ua.w));
    float4 xb = make_float4(bf2f(ub.x), bf2f(ub.y), bf2f(ub.z), bf2f(ub.w));
    float4 xc = make_float4(bf2f(uc.x), bf2f(uc.y), bf2f(uc.z), bf2f(uc.w));
    float4 xd = make_float4(bf2f(ud.x), bf2f(ud.y), bf2f(ud.z), bf2f(ud.w));
    float va, pa = 0.f, pb = 0.f, pc = 0.f, pd = 0.f;
    va = xa.x + xr.x; pa = fmaf(a6.x, va, pa); pa = fmaf(a4.x, fabsf(va), pa);
    va = xa.y + xr.y; pa = fmaf(a6.y, va, pa); pa = fmaf(a4.y, fabsf(va), pa);
    va = xa.z + xr.z; pa = fmaf(a6.z, va, pa); pa = fmaf(a4.z, fabsf(va), pa);
    va = xa.w + xr.w; pa = fmaf(a6.w, va, pa); pa = fmaf(a4.w, fabsf(va), pa);
    va = xb.x + xr.x; pb = fmaf(a6.x, va, pb); pb = fmaf(a4.x, fabsf(va), pb);
    va = xb.y + xr.y; pb = fmaf(a6.y, va, pb); pb = fmaf(a4.y, fabsf(va), pb);
    va = xb.z + xr.z; pb = fmaf(a6.z, va, pb); pb = fmaf(a4.z, fabsf(va), pb);
    va = xb.w + xr.w; pb = fmaf(a6.w, va, pb); pb = fmaf(a4.w, fabsf(va), pb);
    va = xc.x + xr.x; pc = fmaf(a6.x, va, pc); pc = fmaf(a4.x, fabsf(va), pc);
    va = xc.y + xr.y; pc = fmaf(a6.y, va, pc); pc = fmaf(a4.y, fabsf(va), pc);
    va = xc.z + xr.z; pc = fmaf(a6.z, va, pc); pc = fmaf(a4.z, fabsf(va), pc);
    va = xc.w + xr.w; pc = fmaf(a6.w, va, pc); pc = fmaf(a4.w, fabsf(va), pc);
    va = xd.x + xr.x; pd = fmaf(a6.x, va, pd); pd = fmaf(a4.x, fabsf(va), pd);
    va = xd.y + xr.y; pd = fmaf(a6.y, va, pd); pd = fmaf(a4.y, fabsf(va), pd);
    va = xd.z + xr.z; pd = fmaf(a6.z, va, pd); pd = fmaf(a4.z, fabsf(va), pd);
    va = xd.w + xr.w; pd = fmaf(a6.w, va, pd); pd = fmaf(a4.w, fabsf(va), pd);
#pragma unroll
    for (int off = 1; off <= 4; off <<= 1) {
      pa += __shfl_xor(pa, off);
      pb += __shfl_xor(pb, off);
      pc += __shfl_xor(pc, off);
      pd += __shfl_xor(pd, off);
    }
    float wa = exp2f(fminf(pa, 43.f));
    float wb = exp2f(fminf(pb, 43.f));
    float wc = exp2f(fminf(pc, 43.f));
    float wd = exp2f(fminf(pd, 43.f));
    den0 += wa + wc;
    den1 += wb + wd;
    A0.x += wa * xa.x + wc * xc.x;  A1.x += wb * xb.x + wd * xd.x;
    A0.y += wa * xa.y + wc * xc.y;  A1.y += wb * xb.y + wd * xd.y;
    A0.z += wa * xa.z + wc * xc.z;  A1.z += wb * xb.z + wd * xd.z;
    A0.w += wa * xa.w + wc * xc.w;  A1.w += wb * xb.w + wd * xd.w;
  }
  for (; i < s1; ++i) {
    int sa = ssort[i];
    ushort4 ua = *(const ushort4*)&Xl[sa * 128 + l * 4];
    float4 xa = make_float4(bf2f(ua.x), bf2f(ua.y), bf2f(ua.z), bf2f(ua.w));
    float va, pa = 0.f;
    va = xa.x + xr.x; pa = fmaf(a6.x, va, pa); pa = fmaf(a4.x, fabsf(va), pa);
    va = xa.y + xr.y; pa = fmaf(a6.y, va, pa); pa = fmaf(a4.y, fabsf(va), pa);
    va = xa.z + xr.z; pa = fmaf(a6.z, va, pa); pa = fmaf(a4.z, fabsf(va), pa);
    va = xa.w + xr.w; pa = fmaf(a6.w, va, pa); pa = fmaf(a4.w, fabsf(va), pa);
#pragma unroll
    for (int off = 1; off <= 4; off <<= 1) pa += __shfl_xor(pa, off);
    float wa = exp2f(fminf(pa, 43.f));
    den0 += wa;
    A0.x += wa * xa.x; A0.y += wa * xa.y; A0.z += wa * xa.z; A0.w += wa * xa.w;
  }
  float den = den0 + den1;
  float inv = 1.f / (den + 1e-16f);
  float4 b4 = *(const float4*)&bias[l * 4];
  float4 o;
  o.x = (A0.x + A1.x) * inv + b4.x;
  o.y = (A0.y + A1.y) * inv + b4.y;
  o.z = (A0.z + A1.z) * inv + b4.z;
  o.w = (A0.w + A1.w) * inv + b4.w;
  o.x = o.x > 0.f ? o.x : __expf(o.x) - 1.f;
  o.y = o.y > 0.f ? o.y : __expf(o.y) - 1.f;
  o.z = o.z > 0.f ? o.z : __expf(o.z) - 1.f;
  o.w = o.w > 0.f ? o.w : __expf(o.w) - 1.f;
  if (MODE == 0) {
    ushort4 ub;
    ub.x = f2bf(o.x); ub.y = f2bf(o.y); ub.z = f2bf(o.z); ub.w = f2bf(o.w);
    *(ushort4*)&outb[n * 128 + l * 4] = ub;
  } else {
    float4 wl = *(const float4*)&Wl3[l * 4];
    float4 wr = *(const float4*)&Wr3[l * 4];
    float sl = o.x * wl.x + o.y * wl.y + o.z * wl.z + o.w * wl.w;
    float sr = o.x * wr.x + o.y * wr.y + o.z * wr.z + o.w * wr.w;
#pragma unroll
    for (int off = 1; off <= 16; off <<= 1) {
      sl += __shfl_xor(sl, off);
      sr += __shfl_xor(sr, off);
    }
    if (l == 0) {
      xl3[n] = sl + bl3[0];
      xr3[n] = sr + br3[0];
    }
  }
}

// fused layer-3 edge phase: per-node wave, no-max softmax, wave merge
__global__ __launch_bounds__(256) void aggregate3_fused(
    const float* __restrict__ xl3, const float* __restrict__ xr3,
    const float* __restrict__ att, const int* __restrict__ ssort,
    const int* __restrict__ rowptr, const float* __restrict__ bias,
    float* __restrict__ out, int nn) {
  int wid = threadIdx.x >> 6, lane = threadIdx.x & 63;
  int n = blockIdx.x * 4 + wid;
  if (n >= nn) return;
  int s0 = rowptr[n], s1 = rowptr[n + 1];
  float xr = xr3[n];
  const float L2E = 1.44269504f;
  float s6 = 0.6f * L2E * att[0];
  float s4 = 0.4f * L2E * att[0];
  float den = 0.f, acc = 0.f;
  for (int i = s0 + lane; i < s1; i += 64) {
    float xl = xl3[ssort[i]];
    float v = xl + xr;
    float p = fmaf(s6, v, s4 * fabsf(v));
    float w = exp2f(fminf(p, 43.f));
    den += w;
    acc += w * xl;
  }
#pragma unroll
  for (int off = 32; off; off >>= 1) {
    den += __shfl_xor(den, off);
    acc += __shfl_xor(acc, off);
  }
  if (lane == 0) {
    float o = acc / (den + 1e-16f) + bias[0];
    out[n] = 1.f / (1.f + __expf(-o));
  }
}

extern "C" void kernel_launch(void* const* d_in, const int* in_sizes, int n_in,
                              void* d_out, int out_size, void* d_ws, size_t ws_size,
                              hipStream_t stream) {
  const float* x = (const float*)d_in[0];
  const int* ei = (const int*)d_in[1];
  const int* src = ei;
  const int* dst = ei + NE;
  const float* W_l1 = (const float*)d_in[2];
  const float* b_l1 = (const float*)d_in[3];
  const float* W_r1 = (const float*)d_in[4];
  const float* b_r1 = (const float*)d_in[5];
  const float* att1 = (const float*)d_in[6];
  const float* bias1 = (const float*)d_in[7];
  const float* W_l2 = (const float*)d_in[8];
  const float* b_l2 = (const float*)d_in[9];
  const float* W_r2 = (const float*)d_in[10];
  const float* b_r2 = (const float*)d_in[11];
  const float* att2 = (const float*)d_in[12];
  const float* bias2 = (const float*)d_in[13];
  const float* W_l3 = (const float*)d_in[14];
  const float* b_l3 = (const float*)d_in[15];
  const float* W_r3 = (const float*)d_in[16];
  const float* b_r3 = (const float*)d_in[17];
  const float* att3 = (const float*)d_in[18];
  const float* bias3 = (const float*)d_in[19];
  float* out = (float*)d_out;

  ushort* xbb = (ushort*)d_ws;           // NN*128 bf16 (gemm A input)
  ushort* xl_b = xbb + NN * 128;         // NN*128 bf16
  ushort* xr_b = xl_b + NN * 128;        // NN*128 bf16
  ushort* bpack = xr_b + NN * 128;       // 32768 bf16 packed weights
  int* deg = (int*)(bpack + 32768);      // NN
  int* rowptr = deg + NN;                // NN+1
  int* bcur = rowptr + NN + 1;           // NBUK
  int* bsum = bcur + NBUK;               // 256
  int* boff = bsum + 256;                // 256
  int* ssort = boff + 256;               // NE
  int2* pairs = (int2*)(ssort + NE);     // NE int2
  float* xl3 = (float*)(pairs + NE);     // NN
  float* xr3 = xl3 + NN;                 // NN

  const int NB_N = (NN + 255) / 256;     // 196
  const int NB_E = (NE + 255) / 256;     // 3125
  const int NB_G = (NN + 63) / 64;       // 782
  const int NB_A = (NN + 7) / 8;         // 6250
  const int NB_W4 = (NN + 3) / 4;        // 12500
  const int NB_C = (NN * 128 / 8 + 255) / 256;  // 3125
  const int NB_BK = (NE + 4095) / 4096;  // 196

  // ---- CSR build (bucketed counting sort) ----
  zero_i32<<<NB_N, 256, 0, stream>>>(deg, NN);
  hist_kernel<<<NB_E, 256, 0, stream>>>(dst, deg);
  scan_a<<<NB_N, 256, 0, stream>>>(deg, rowptr, bsum, NN);
  scan_a<<<1, 256, 0, stream>>>(bsum, boff, (int*)nullptr, NB_N);
  scan_c<<<NB_N + 1, 256, 0, stream>>>(rowptr, boff, bcur, NN);
  bucket_scatter<<<NB_BK, 256, 0, stream>>>(src, dst, bcur, pairs);
  bucket_sort<<<NBUK, 256, 0, stream>>>(pairs, rowptr, ssort);

  // ---- layer 1 ----
  cvt_bf16<<<NB_C, 256, 0, stream>>>(x, xbb, NN * 128 / 8);
  pack_w<<<16, 256, 0, stream>>>(W_l1, W_r1, bpack);
  gemm_mfma<<<NB_G, 256, 0, stream>>>(xbb, bpack, b_l1, b_r1, xl_b, xr_b, NN);
  gat_aggregate<0><<<NB_A, 256, 0, stream>>>(xl_b, xr_b, att1, ssort, rowptr, bias1,
                                             xbb, nullptr, nullptr, nullptr, nullptr,
                                             nullptr, nullptr);

  // ---- layer 2 (+ fused layer-3 GEMV epilogue) ----
  pack_w<<<16, 256, 0, stream>>>(W_l2, W_r2, bpack);
  gemm_mfma<<<NB_G, 256, 0, stream>>>(xbb, bpack, b_l2, b_r2, xl_b, xr_b, NN);
  gat_aggregate<1><<<NB_A, 256, 0, stream>>>(xl_b, xr_b, att2, ssort, rowptr, bias2,
                                             nullptr, W_l3, W_r3, b_l3, b_r3,
                                             xl3, xr3);

  // ---- layer 3 edge phase ----
  aggregate3_fused<<<NB_W4, 256, 0, stream>>>(xl3, xr3, att3, ssort, rowptr, bias3, out, NN);
}

// Round 14
// 309.919 us; speedup vs baseline: 1.5676x; 1.0068x over previous
//
#include <hip/hip_runtime.h>
#include <hip/hip_bf16.h>
#include <math.h>

#define NN 50000
#define NE 800000
#define NBUK 391      // ceil(NN/128)
#define BNODES 128

typedef __attribute__((ext_vector_type(8))) short bf16x8;
typedef __attribute__((ext_vector_type(4))) float f32x4;
typedef __attribute__((ext_vector_type(8))) unsigned short ushort8v;

__device__ __forceinline__ ushort f2bf(float v) {
  __hip_bfloat16 h = __float2bfloat16(v);
  return *(ushort*)&h;
}
__device__ __forceinline__ float bf2f(ushort u) {
  return __uint_as_float(((unsigned int)u) << 16);
}

// -------- pack Wl|Wr (fp32 [128][128] each) into MFMA B-frag bf16 layout ---
__global__ void pack_w(const float* __restrict__ Wl, const float* __restrict__ Wr,
                       ushort* __restrict__ Bpack) {
  int t = blockIdx.x * 256 + threadIdx.x;   // (kt,col,hi): 4*256*4 = 4096
  if (t >= 4096) return;
  int hi = t & 3;
  int col = (t >> 2) & 255;
  int kt = t >> 10;
  const float* W = (col < 128) ? (Wl + col) : (Wr + (col - 128));
  ushort4 u0, u1;
  int k0 = kt * 32 + hi * 8;
  u0.x = f2bf(W[(k0 + 0) * 128]); u0.y = f2bf(W[(k0 + 1) * 128]);
  u0.z = f2bf(W[(k0 + 2) * 128]); u0.w = f2bf(W[(k0 + 3) * 128]);
  u1.x = f2bf(W[(k0 + 4) * 128]); u1.y = f2bf(W[(k0 + 5) * 128]);
  u1.z = f2bf(W[(k0 + 6) * 128]); u1.w = f2bf(W[(k0 + 7) * 128]);
  *(ushort4*)&Bpack[t * 8] = u0;
  *(ushort4*)&Bpack[t * 8 + 4] = u1;
}

// -------- MFMA dual GEMM: [Xl|Xr](bf16) = A @ [Wl|Wr] + [bl|br] -----------
// AF32=1: A is fp32 (layer 1, converts in-register); else A is bf16.
// LDS-staged coalesced epilogue (ushort8 stores).
template <int AF32>
__global__ __launch_bounds__(256) void gemm_mfma(
    const void* __restrict__ Aptr, const ushort* __restrict__ Bpack,
    const float* __restrict__ bl, const float* __restrict__ br,
    ushort* __restrict__ Xl, ushort* __restrict__ Xr, int n) {
  __shared__ ushort tile[64][264];   // row stride 528B (16B-aligned)
  const int tid = threadIdx.x;
  const int wv = tid >> 6;
  const int l = tid & 63;
  const int lr = l & 15;
  const int hi = l >> 4;
  const int r0 = blockIdx.x * 64;

  f32x4 acc[4][4];
#pragma unroll
  for (int mi = 0; mi < 4; ++mi)
#pragma unroll
    for (int nj = 0; nj < 4; ++nj) acc[mi][nj] = (f32x4)0.f;

#pragma unroll
  for (int kt = 0; kt < 4; ++kt) {
    bf16x8 b[4], a[4];
#pragma unroll
    for (int nj = 0; nj < 4; ++nj) {
      int col = wv * 64 + nj * 16 + lr;
      b[nj] = *(const bf16x8*)&Bpack[((kt * 256 + col) * 4 + hi) * 8];
    }
#pragma unroll
    for (int mi = 0; mi < 4; ++mi) {
      int row = r0 + mi * 16 + lr;
      row = row < n ? row : n - 1;     // clamp tail reads (stores guarded)
      if (AF32) {
        const float* Af = (const float*)Aptr;
        float4 f0 = *(const float4*)&Af[row * 128 + kt * 32 + hi * 8];
        float4 f1 = *(const float4*)&Af[row * 128 + kt * 32 + hi * 8 + 4];
        bf16x8 av;
        av[0] = (short)f2bf(f0.x); av[1] = (short)f2bf(f0.y);
        av[2] = (short)f2bf(f0.z); av[3] = (short)f2bf(f0.w);
        av[4] = (short)f2bf(f1.x); av[5] = (short)f2bf(f1.y);
        av[6] = (short)f2bf(f1.z); av[7] = (short)f2bf(f1.w);
        a[mi] = av;
      } else {
        const ushort* Ab = (const ushort*)Aptr;
        a[mi] = *(const bf16x8*)&Ab[row * 128 + kt * 32 + hi * 8];
      }
    }
#pragma unroll
    for (int mi = 0; mi < 4; ++mi)
#pragma unroll
      for (int nj = 0; nj < 4; ++nj)
        acc[mi][nj] = __builtin_amdgcn_mfma_f32_16x16x32_bf16(a[mi], b[nj], acc[mi][nj], 0, 0, 0);
  }

  // acc -> LDS (bias added)
#pragma unroll
  for (int nj = 0; nj < 4; ++nj) {
    int col = wv * 64 + nj * 16 + lr;
    float bb = (col < 128) ? bl[col] : br[col - 128];
#pragma unroll
    for (int mi = 0; mi < 4; ++mi)
#pragma unroll
      for (int v = 0; v < 4; ++v)
        tile[mi * 16 + hi * 4 + v][col] = f2bf(acc[mi][nj][v] + bb);
  }
  __syncthreads();

  // coalesced store: 8 chunks of 16B per thread
#pragma unroll
  for (int j = 0; j < 8; ++j) {
    int c = j * 256 + tid;          // 0..2047
    int rl = c >> 5;                // local row
    int colc = (c & 31) * 8;        // col chunk start
    int row = r0 + rl;
    if (row < n) {
      ushort* dstp = (colc < 128) ? &Xl[row * 128 + colc] : &Xr[row * 128 + (colc - 128)];
      *(ushort8v*)dstp = *(const ushort8v*)&tile[rl][colc];
    }
  }
}

// ---------------- CSR build ----------------
__global__ void zero_i32(int* p, int n) {
  int i = blockIdx.x * 256 + threadIdx.x;
  if (i < n) p[i] = 0;
}

__global__ void hist_kernel(const int* __restrict__ dst, int* __restrict__ deg) {
  int e = blockIdx.x * 256 + threadIdx.x;
  if (e < NE) atomicAdd(&deg[dst[e]], 1);
}

__global__ __launch_bounds__(256) void scan_a(const int* __restrict__ in,
                                              int* __restrict__ excl,
                                              int* __restrict__ bsum, int n) {
  int i = blockIdx.x * 256 + threadIdx.x;
  int v = (i < n) ? in[i] : 0;
  int lane = threadIdx.x & 63, wid = threadIdx.x >> 6;
  int incl = v;
#pragma unroll
  for (int off = 1; off < 64; off <<= 1) {
    int u = __shfl_up(incl, off);
    if (lane >= off) incl += u;
  }
  __shared__ int wsum[4];
  if (lane == 63) wsum[wid] = incl;
  __syncthreads();
  int wo = 0;
  for (int w = 0; w < wid; w++) wo += wsum[w];
  if (i < n) excl[i] = wo + incl - v;
  if (threadIdx.x == 255 && bsum) bsum[blockIdx.x] = wo + incl;
}

// finalize rowptr and init per-bucket cursors (bcur[b] = rowptr[b*128])
__global__ void scan_c(int* __restrict__ rowptr, const int* __restrict__ boff,
                       int* __restrict__ bcur, int n) {
  int i = blockIdx.x * 256 + threadIdx.x;
  if (i < n) {
    int v = rowptr[i] + boff[i >> 8];
    rowptr[i] = v;
    if ((i & 127) == 0) bcur[i >> 7] = v;
  } else if (i == n) {
    rowptr[n] = NE;
  }
}

// pass A: coarse-bucket edges (bucket = dst>>7) into bucket-major pairs.
__global__ __launch_bounds__(256) void bucket_scatter(
    const int* __restrict__ src, const int* __restrict__ dst,
    int* __restrict__ bcur, int2* __restrict__ pairs) {
  __shared__ int cnt[NBUK];
  __shared__ int base[NBUK];
  const int t = threadIdx.x;
  for (int i = t; i < NBUK; i += 256) cnt[i] = 0;
  __syncthreads();
  const int e0 = blockIdx.x * 4096;
#pragma unroll
  for (int j = 0; j < 16; ++j) {
    int e = e0 + j * 256 + t;
    if (e < NE) atomicAdd(&cnt[dst[e] >> 7], 1);
  }
  __syncthreads();
  for (int i = t; i < NBUK; i += 256) {
    int c = cnt[i];
    base[i] = c ? atomicAdd(&bcur[i], c) : 0;
    cnt[i] = 0;
  }
  __syncthreads();
#pragma unroll
  for (int j = 0; j < 16; ++j) {
    int e = e0 + j * 256 + t;
    if (e < NE) {
      int d = dst[e];
      int b = d >> 7;
      int r = atomicAdd(&cnt[b], 1);
      pairs[base[b] + r] = make_int2(src[e], d);
    }
  }
}

// pass B: per-bucket fine sort with LDS cursors.
__global__ __launch_bounds__(256) void bucket_sort(
    const int2* __restrict__ pairs, const int* __restrict__ rowptr,
    int* __restrict__ ssort) {
  __shared__ int cur[BNODES];
  const int b = blockIdx.x;
  const int n0 = b * BNODES;
  const int t = threadIdx.x;
  const int n1 = min(n0 + BNODES, NN);
  if (t < BNODES && n0 + t < NN) cur[t] = rowptr[n0 + t];
  __syncthreads();
  const int e0 = rowptr[n0];
  const int e1 = rowptr[n1];
  for (int e = e0 + t; e < e1; e += 256) {
    int2 p = pairs[e];
    int pos = atomicAdd(&cur[p.y - n0], 1);
    ssort[pos] = p.x;
  }
}

// ------- fused: logits + segment-softmax + aggregate + bias + ELU ---------
// 16 lanes/node x 8 channels/lane (ushort8 gathers, head = 4 lanes -> 2 shfl
// levels). Branchless logit: att*lrelu(v) = .6att*v + .4att*|v|, log2e folded.
template <int MODE>
__global__ __launch_bounds__(256) void gat_aggregate(
    const ushort* __restrict__ Xl, const ushort* __restrict__ Xr,
    const float* __restrict__ att, const int* __restrict__ ssort,
    const int* __restrict__ rowptr, const float* __restrict__ bias,
    ushort* __restrict__ outb,
    const float* __restrict__ Wl3, const float* __restrict__ Wr3,
    const float* __restrict__ bl3, const float* __restrict__ br3,
    float* __restrict__ xl3, float* __restrict__ xr3) {
  int slot = threadIdx.x >> 4;        // 16 nodes per block
  int l = threadIdx.x & 15;           // lane in node; head = l>>2
  int n = blockIdx.x * 16 + slot;
  if (n >= NN) return;
  int s0 = rowptr[n], s1 = rowptr[n + 1];
  ushort8v xru = *(const ushort8v*)&Xr[n * 128 + l * 8];
  const float L2E = 1.44269504f;
  float xr[8], a6[8], a4[8];
#pragma unroll
  for (int c = 0; c < 8; ++c) {
    xr[c] = bf2f(xru[c]);
    float a = att[l * 8 + c];
    a6[c] = 0.6f * L2E * a;
    a4[c] = 0.4f * L2E * a;
  }
  float den = 0.f;
  float A0[8], A1[8];
#pragma unroll
  for (int c = 0; c < 8; ++c) { A0[c] = 0.f; A1[c] = 0.f; }

  int i = s0;
  for (; i + 4 <= s1; i += 4) {
    int sa = ssort[i], sb = ssort[i + 1], sc = ssort[i + 2], sd = ssort[i + 3];
    ushort8v ua = *(const ushort8v*)&Xl[sa * 128 + l * 8];
    ushort8v ub = *(const ushort8v*)&Xl[sb * 128 + l * 8];
    ushort8v uc = *(const ushort8v*)&Xl[sc * 128 + l * 8];
    ushort8v ud = *(const ushort8v*)&Xl[sd * 128 + l * 8];
    float xa[8], xb[8], xc[8], xd[8];
    float pa = 0.f, pb = 0.f, pc = 0.f, pd = 0.f;
#pragma unroll
    for (int c = 0; c < 8; ++c) {
      float va;
      xa[c] = bf2f(ua[c]); va = xa[c] + xr[c];
      pa = fmaf(a6[c], va, pa); pa = fmaf(a4[c], fabsf(va), pa);
      xb[c] = bf2f(ub[c]); va = xb[c] + xr[c];
      pb = fmaf(a6[c], va, pb); pb = fmaf(a4[c], fabsf(va), pb);
      xc[c] = bf2f(uc[c]); va = xc[c] + xr[c];
      pc = fmaf(a6[c], va, pc); pc = fmaf(a4[c], fabsf(va), pc);
      xd[c] = bf2f(ud[c]); va = xd[c] + xr[c];
      pd = fmaf(a6[c], va, pd); pd = fmaf(a4[c], fabsf(va), pd);
    }
    pa += __shfl_xor(pa, 1); pa += __shfl_xor(pa, 2);
    pb += __shfl_xor(pb, 1); pb += __shfl_xor(pb, 2);
    pc += __shfl_xor(pc, 1); pc += __shfl_xor(pc, 2);
    pd += __shfl_xor(pd, 1); pd += __shfl_xor(pd, 2);
    float wa = exp2f(fminf(pa, 43.f));
    float wb = exp2f(fminf(pb, 43.f));
    float wc = exp2f(fminf(pc, 43.f));
    float wd = exp2f(fminf(pd, 43.f));
    den += (wa + wb) + (wc + wd);
#pragma unroll
    for (int c = 0; c < 8; ++c) {
      A0[c] = fmaf(wa, xa[c], A0[c]); A1[c] = fmaf(wb, xb[c], A1[c]);
      A0[c] = fmaf(wc, xc[c], A0[c]); A1[c] = fmaf(wd, xd[c], A1[c]);
    }
  }
  for (; i < s1; ++i) {
    int sa = ssort[i];
    ushort8v ua = *(const ushort8v*)&Xl[sa * 128 + l * 8];
    float xa[8], pa = 0.f;
#pragma unroll
    for (int c = 0; c < 8; ++c) {
      xa[c] = bf2f(ua[c]);
      float va = xa[c] + xr[c];
      pa = fmaf(a6[c], va, pa); pa = fmaf(a4[c], fabsf(va), pa);
    }
    pa += __shfl_xor(pa, 1); pa += __shfl_xor(pa, 2);
    float wa = exp2f(fminf(pa, 43.f));
    den += wa;
#pragma unroll
    for (int c = 0; c < 8; ++c) A0[c] = fmaf(wa, xa[c], A0[c]);
  }
  float inv = 1.f / (den + 1e-16f);
  float o[8];
#pragma unroll
  for (int c = 0; c < 8; ++c) {
    o[c] = (A0[c] + A1[c]) * inv + bias[l * 8 + c];
    o[c] = o[c] > 0.f ? o[c] : __expf(o[c]) - 1.f;
  }
  if (MODE == 0) {
    ushort8v ub;
#pragma unroll
    for (int c = 0; c < 8; ++c) ub[c] = f2bf(o[c]);
    *(ushort8v*)&outb[n * 128 + l * 8] = ub;
  } else {
    float sl = 0.f, sr = 0.f;
#pragma unroll
    for (int c = 0; c < 8; ++c) {
      sl = fmaf(o[c], Wl3[l * 8 + c], sl);
      sr = fmaf(o[c], Wr3[l * 8 + c], sr);
    }
#pragma unroll
    for (int off = 1; off <= 8; off <<= 1) {
      sl += __shfl_xor(sl, off);
      sr += __shfl_xor(sr, off);
    }
    if (l == 0) {
      xl3[n] = sl + bl3[0];
      xr3[n] = sr + br3[0];
    }
  }
}

// fused layer-3 edge phase: per-node wave, no-max softmax, wave merge
__global__ __launch_bounds__(256) void aggregate3_fused(
    const float* __restrict__ xl3, const float* __restrict__ xr3,
    const float* __restrict__ att, const int* __restrict__ ssort,
    const int* __restrict__ rowptr, const float* __restrict__ bias,
    float* __restrict__ out, int nn) {
  int wid = threadIdx.x >> 6, lane = threadIdx.x & 63;
  int n = blockIdx.x * 4 + wid;
  if (n >= nn) return;
  int s0 = rowptr[n], s1 = rowptr[n + 1];
  float xr = xr3[n];
  const float L2E = 1.44269504f;
  float s6 = 0.6f * L2E * att[0];
  float s4 = 0.4f * L2E * att[0];
  float den = 0.f, acc = 0.f;
  for (int i = s0 + lane; i < s1; i += 64) {
    float xl = xl3[ssort[i]];
    float v = xl + xr;
    float p = fmaf(s6, v, s4 * fabsf(v));
    float w = exp2f(fminf(p, 43.f));
    den += w;
    acc += w * xl;
  }
#pragma unroll
  for (int off = 32; off; off >>= 1) {
    den += __shfl_xor(den, off);
    acc += __shfl_xor(acc, off);
  }
  if (lane == 0) {
    float o = acc / (den + 1e-16f) + bias[0];
    out[n] = 1.f / (1.f + __expf(-o));
  }
}

extern "C" void kernel_launch(void* const* d_in, const int* in_sizes, int n_in,
                              void* d_out, int out_size, void* d_ws, size_t ws_size,
                              hipStream_t stream) {
  const float* x = (const float*)d_in[0];
  const int* ei = (const int*)d_in[1];
  const int* src = ei;
  const int* dst = ei + NE;
  const float* W_l1 = (const float*)d_in[2];
  const float* b_l1 = (const float*)d_in[3];
  const float* W_r1 = (const float*)d_in[4];
  const float* b_r1 = (const float*)d_in[5];
  const float* att1 = (const float*)d_in[6];
  const float* bias1 = (const float*)d_in[7];
  const float* W_l2 = (const float*)d_in[8];
  const float* b_l2 = (const float*)d_in[9];
  const float* W_r2 = (const float*)d_in[10];
  const float* b_r2 = (const float*)d_in[11];
  const float* att2 = (const float*)d_in[12];
  const float* bias2 = (const float*)d_in[13];
  const float* W_l3 = (const float*)d_in[14];
  const float* b_l3 = (const float*)d_in[15];
  const float* W_r3 = (const float*)d_in[16];
  const float* b_r3 = (const float*)d_in[17];
  const float* att3 = (const float*)d_in[18];
  const float* bias3 = (const float*)d_in[19];
  float* out = (float*)d_out;

  ushort* xbb = (ushort*)d_ws;           // NN*128 bf16 (layer-2 gemm A input)
  ushort* xl_b = xbb + NN * 128;         // NN*128 bf16
  ushort* xr_b = xl_b + NN * 128;        // NN*128 bf16
  ushort* bpack = xr_b + NN * 128;       // 32768 bf16 packed weights
  int* deg = (int*)(bpack + 32768);      // NN
  int* rowptr = deg + NN;                // NN+1
  int* bcur = rowptr + NN + 1;           // NBUK
  int* bsum = bcur + NBUK;               // 256
  int* boff = bsum + 256;                // 256
  int* ssort = boff + 256;               // NE
  int2* pairs = (int2*)(ssort + NE);     // NE int2
  float* xl3 = (float*)(pairs + NE);     // NN
  float* xr3 = xl3 + NN;                 // NN

  const int NB_N = (NN + 255) / 256;     // 196
  const int NB_E = (NE + 255) / 256;     // 3125
  const int NB_G = (NN + 63) / 64;       // 782
  const int NB_A = (NN + 15) / 16;       // 3125
  const int NB_W4 = (NN + 3) / 4;        // 12500
  const int NB_BK = (NE + 4095) / 4096;  // 196

  // ---- CSR build (bucketed counting sort) ----
  zero_i32<<<NB_N, 256, 0, stream>>>(deg, NN);
  hist_kernel<<<NB_E, 256, 0, stream>>>(dst, deg);
  scan_a<<<NB_N, 256, 0, stream>>>(deg, rowptr, bsum, NN);
  scan_a<<<1, 256, 0, stream>>>(bsum, boff, (int*)nullptr, NB_N);
  scan_c<<<NB_N + 1, 256, 0, stream>>>(rowptr, boff, bcur, NN);
  bucket_scatter<<<NB_BK, 256, 0, stream>>>(src, dst, bcur, pairs);
  bucket_sort<<<NBUK, 256, 0, stream>>>(pairs, rowptr, ssort);

  // ---- layer 1 (A = fp32 x, converted in-register) ----
  pack_w<<<16, 256, 0, stream>>>(W_l1, W_r1, bpack);
  gemm_mfma<1><<<NB_G, 256, 0, stream>>>(x, bpack, b_l1, b_r1, xl_b, xr_b, NN);
  gat_aggregate<0><<<NB_A, 256, 0, stream>>>(xl_b, xr_b, att1, ssort, rowptr, bias1,
                                             xbb, nullptr, nullptr, nullptr, nullptr,
                                             nullptr, nullptr);

  // ---- layer 2 (+ fused layer-3 GEMV epilogue) ----
  pack_w<<<16, 256, 0, stream>>>(W_l2, W_r2, bpack);
  gemm_mfma<0><<<NB_G, 256, 0, stream>>>(xbb, bpack, b_l2, b_r2, xl_b, xr_b, NN);
  gat_aggregate<1><<<NB_A, 256, 0, stream>>>(xl_b, xr_b, att2, ssort, rowptr, bias2,
                                             nullptr, W_l3, W_r3, b_l3, b_r3,
                                             xl3, xr3);

  // ---- layer 3 edge phase ----
  aggregate3_fused<<<NB_W4, 256, 0, stream>>>(xl3, xr3, att3, ssort, rowptr, bias3, out, NN);
}